// Round 10
// baseline (180.034 us; speedup 1.0000x reference)
//
#include <hip/hip_runtime.h>

// MAB block, MFMA bf16, round 16: transposed-accumulator GEMM epilogues.
// r15 post-mortem: attn <= ~40us; the ~137us non-attn mid-section (constant
// since r0) is the target. All three GEMM kernels wrote C as 16 scalar
// ushort stores/thread (128B/wave-instr). r16 swaps MFMA operand order
// (mfma(wf, a, acc)) so acc regs span 4 CONSECUTIVE cols (D[X-idx=4q+r]
// [Y-idx=l15] rule, verified by the attn kernel's od handling):
// -> shortx4 packed stores, 4/thread, 512B contiguous per wave-instr (4x);
// -> gemm_ffn2_ln gets fx4 bias/g/be/R loads + fx4 out stores + simpler
//    lane-resident LN row-reduce. MFMA core, staging, layouts unchanged.

typedef float fx4 __attribute__((ext_vector_type(4)));
typedef short short8 __attribute__((ext_vector_type(8)));
typedef short shortx4 __attribute__((ext_vector_type(4)));
typedef unsigned int uint2v __attribute__((ext_vector_type(2)));
typedef unsigned int uint4v __attribute__((ext_vector_type(4)));

#define BB  4
#define NN  2048
#define DD  256
#define HH  4
#define DHH 64

__device__ __forceinline__ float bf2f(unsigned short u) {
    union { unsigned int i; float f; } v; v.i = ((unsigned int)u) << 16; return v.f;
}
__device__ __forceinline__ unsigned short f2bf(float f) {
    union { float f; unsigned int i; } v; v.f = f;
    unsigned int r = v.i + 0x7FFF + ((v.i >> 16) & 1);   // RNE
    return (unsigned short)(r >> 16);
}
__device__ __forceinline__ unsigned int fbits(float f) {
    union { float f; unsigned int i; } v; v.f = f; return v.i;
}
__device__ __forceinline__ unsigned int packbf(float lo, float hi) {
    unsigned int a = fbits(lo), b = fbits(hi);
    a = (a + 0x7FFF + ((a >> 16) & 1)) >> 16;
    b = (b + 0x7FFF + ((b >> 16) & 1)) & 0xFFFF0000u;
    return a | b;
}

// ---------------------------------------------------------------------------
// Weight prep: WT[n][k] = bf16(W[k][n]) for the 5 weight matrices (256x256).
// ---------------------------------------------------------------------------
__global__ __launch_bounds__(256) void wt_prep(
        const float* __restrict__ w0, const float* __restrict__ w1,
        const float* __restrict__ w2, const float* __restrict__ w3,
        const float* __restrict__ w4, unsigned short* __restrict__ dst) {
    __shared__ unsigned short T[64 * 73];
    const int tid = threadIdx.x;
    const int z = blockIdx.z;
    const float* W = (z == 0) ? w0 : (z == 1) ? w1 : (z == 2) ? w2 : (z == 3) ? w3 : w4;
    unsigned short* WT = dst + z * 65536;
    const int nb = blockIdx.x * 64, kb = blockIdx.y * 64;
    {
        int kl = tid >> 2, c0 = (tid & 3) * 16;
        const float* src = W + (size_t)(kb + kl) * DD + nb + c0;
#pragma unroll
        for (int i = 0; i < 16; ++i) T[kl * 73 + c0 + i] = f2bf(src[i]);
    }
    __syncthreads();
    {
        int nl = tid >> 2, k0 = (tid & 3) * 16;
        short8 o0, o1;
#pragma unroll
        for (int i = 0; i < 8; ++i) {
            o0[i] = (short)T[(k0 + i) * 73 + nl];
            o1[i] = (short)T[(k0 + 8 + i) * 73 + nl];
        }
        short8* d = (short8*)(WT + (size_t)(nb + nl) * DD + kb + k0);
        d[0] = o0; d[1] = o1;
    }
}

// ---------------------------------------------------------------------------
// V tile-transpose: VT2[bh][tile][d64][key32] <- Vp[b*2048+key][h*64+d].
// grid(128,4): b = bx>>5, keyb = (bx&31)*64 (2 tiles), hb = by.
// ---------------------------------------------------------------------------
__global__ __launch_bounds__(256) void vt_prep(
        const unsigned short* __restrict__ Vp, unsigned short* __restrict__ VT2) {
    __shared__ unsigned short T[64 * 73];
    const int tid = threadIdx.x;
    const int hb = blockIdx.y;
    const int b = blockIdx.x >> 5;
    const int keyb = (blockIdx.x & 31) * 64;
    const int bh = b * HH + hb;
    {
        int kl = tid >> 2, c0 = (tid & 3) * 16;
        const short8* src = (const short8*)(Vp + (size_t)(b * NN + keyb + kl) * DD + hb * DHH + c0);
        short8 v0 = src[0], v1 = src[1];
#pragma unroll
        for (int i = 0; i < 8; ++i) {
            T[kl * 73 + c0 + i]     = (unsigned short)v0[i];
            T[kl * 73 + c0 + 8 + i] = (unsigned short)v1[i];
        }
    }
    __syncthreads();
    {
        int dl = tid >> 2, k0 = (tid & 3) * 16;          // d row, key chunk (16)
        short8 o0, o1;
#pragma unroll
        for (int i = 0; i < 8; ++i) {
            o0[i] = (short)T[(k0 + i) * 73 + dl];
            o1[i] = (short)T[(k0 + 8 + i) * 73 + dl];
        }
        const int gkey = keyb + k0;                       // multiple of 16
        const int tl = gkey >> 5;                         // tile index
        const int kin = gkey & 31;                        // 0 or 16
        short8* d = (short8*)(VT2 + ((size_t)(bh * 64 + tl) * 64 + dl) * 32 + kin);
        d[0] = o0; d[1] = o1;
    }
}

// ---------------------------------------------------------------------------
// K tile-permute: KT[bh][tile][dhalf][key32][d32] <- Kp[b*2048+key][h*64+d].
// Pure 16B-chunk permutation; grid 1024 = bh*64 + tile, 256 threads.
// ---------------------------------------------------------------------------
__global__ __launch_bounds__(256) void kt_prep(
        const unsigned short* __restrict__ Kp, unsigned short* __restrict__ KT) {
    const int bh = blockIdx.x >> 6;
    const int tl = blockIdx.x & 63;
    const int b = bh >> 2, h = bh & 3;
    const int tid = threadIdx.x;
    const int key = tid >> 3, p = tid & 7;
    short8 v = *(const short8*)(Kp + (size_t)(b * NN + tl * 32 + key) * DD + h * DHH + p * 8);
    unsigned short* dst = KT + (size_t)(bh * 64 + tl) * 2048
                        + (p >> 2) * 1024 + key * 32 + (p & 3) * 8;
    *(short8*)dst = v;
}

// ---------------------------------------------------------------------------
// 32-row GEMM body: C[r0..r0+32, c-half] = A @ W + bias. 4 waves, wave =
// 32 rows x 32 cols. W-frags hoisted. AIN: 0 fp32 A, 1 bf16 A.
// EP: 0 bias->bf16, 1 relu->bf16.
// r16: transposed accumulator (mfma(wf, a, acc)) -> acc[mt][dt][r] =
// C[r0+mt*16+l15][c0w+dt*16+4*quad+r] -> shortx4 packed stores.
// ---------------------------------------------------------------------------
template<int AIN, int EP>
__device__ __forceinline__ void gemm32_body(
        const void* __restrict__ Ain, const unsigned short* __restrict__ WT,
        const float* __restrict__ bias, void* __restrict__ Cout, int bx) {
    __shared__ unsigned short As[32 * 264];
    const int tid = threadIdx.x;
    const int lane = tid & 63, w = tid >> 6;
    const int l15 = lane & 15, quad = lane >> 4;
    const int r0 = (bx >> 1) * 32;
    const int c0w = (bx & 1) * 128 + w * 32;
    short8 wf[8][2];
#pragma unroll
    for (int kc = 0; kc < 8; ++kc)
#pragma unroll
        for (int dt = 0; dt < 2; ++dt)
            wf[kc][dt] = *(const short8*)(WT + (size_t)(c0w + dt * 16 + l15) * DD + kc * 32 + 8 * quad);
    fx4 bb[2];
#pragma unroll
    for (int dt = 0; dt < 2; ++dt)
        bb[dt] = *(const fx4*)(bias + c0w + dt * 16 + 4 * quad);
    {   // stage A tile (32 x 256) as bf16; thread: 32 elems
        int row = tid >> 3, c0 = (tid & 7) * 32;
        short8 o[4];
        if (AIN == 0) {
            const fx4* s4 = (const fx4*)((const float*)Ain + (size_t)(r0 + row) * DD + c0);
#pragma unroll
            for (int j = 0; j < 4; ++j) {
                fx4 v0 = s4[2 * j], v1 = s4[2 * j + 1];
#pragma unroll
                for (int i = 0; i < 4; ++i) {
                    o[j][i]     = (short)f2bf(v0[i]);
                    o[j][i + 4] = (short)f2bf(v1[i]);
                }
            }
        } else {
            const short8* s8 = (const short8*)((const unsigned short*)Ain + (size_t)(r0 + row) * DD + c0);
#pragma unroll
            for (int j = 0; j < 4; ++j) o[j] = s8[j];
        }
        short8* d = (short8*)(As + row * 264 + c0);
#pragma unroll
        for (int j = 0; j < 4; ++j) d[j] = o[j];
    }
    __syncthreads();
    fx4 acc[2][2];
#pragma unroll
    for (int mt = 0; mt < 2; ++mt)
#pragma unroll
        for (int dt = 0; dt < 2; ++dt) acc[mt][dt] = (fx4){0.f, 0.f, 0.f, 0.f};
#pragma unroll
    for (int kc = 0; kc < 8; ++kc) {
        short8 a0 = *(const short8*)(As + l15 * 264 + kc * 32 + 8 * quad);
        short8 a1 = *(const short8*)(As + (16 + l15) * 264 + kc * 32 + 8 * quad);
#pragma unroll
        for (int dt = 0; dt < 2; ++dt) {
            acc[0][dt] = __builtin_amdgcn_mfma_f32_16x16x32_bf16(wf[kc][dt], a0, acc[0][dt], 0, 0, 0);
            acc[1][dt] = __builtin_amdgcn_mfma_f32_16x16x32_bf16(wf[kc][dt], a1, acc[1][dt], 0, 0, 0);
        }
    }
#pragma unroll
    for (int mt = 0; mt < 2; ++mt) {
        const size_t grow = r0 + mt * 16 + l15;
#pragma unroll
        for (int dt = 0; dt < 2; ++dt) {
            shortx4 pk;
#pragma unroll
            for (int r = 0; r < 4; ++r) {
                float v = acc[mt][dt][r] + bb[dt][r];
                if (EP == 1) v = fmaxf(v, 0.0f);
                pk[r] = (short)f2bf(v);
            }
            *(shortx4*)((unsigned short*)Cout + grow * DD + c0w + dt * 16 + 4 * quad) = pk;
        }
    }
}

// Fused QKV projections: grid (512, 3); y selects {Q->Qp, K->Kp, K->Vp}.
__global__ __launch_bounds__(256, 4) void qkv_mfma(
        const float* __restrict__ Q, const float* __restrict__ K,
        const unsigned short* __restrict__ WT5,
        const float* __restrict__ bq, const float* __restrict__ bk,
        const float* __restrict__ bv,
        unsigned short* __restrict__ Qp, unsigned short* __restrict__ Kp,
        unsigned short* __restrict__ Vp) {
    const int z = blockIdx.y;
    const float* A = (z == 0) ? Q : K;
    const float* bias = (z == 0) ? bq : (z == 1) ? bk : bv;
    unsigned short* C = (z == 0) ? Qp : (z == 1) ? Kp : Vp;
    gemm32_body<0, 0>(A, WT5 + z * 65536, bias, C, blockIdx.x);
}

// FFN1: H1 = relu(O @ W1 + b1), O fp32.
__global__ __launch_bounds__(256, 4) void ffn1_mfma(
        const float* __restrict__ O, const unsigned short* __restrict__ WT1,
        const float* __restrict__ b1, unsigned short* __restrict__ H1) {
    gemm32_body<0, 1>(O, WT1, b1, H1, blockIdx.x);
}

// ---------------------------------------------------------------------------
// FFN2 + residual + LayerNorm fused: out = LN(R + A@W2 + b2), fp32 out.
// Block = 16 rows x 256 cols, 8 waves (wave = 16x32), W-frags hoisted.
// r16: transposed accumulator -> row = l15 lane-resident; fx4 bias/g/be/R
// loads, fx4 out stores; LN row-reduce = 2 shfl (quads) + 8-wave LDS combine.
// ---------------------------------------------------------------------------
__global__ __launch_bounds__(512, 4) void gemm_ffn2_ln(
        const unsigned short* __restrict__ Ain, const unsigned short* __restrict__ WT,
        const float* __restrict__ bias, const float* __restrict__ R,
        const float* __restrict__ g, const float* __restrict__ be,
        float* __restrict__ out) {
    __shared__ unsigned short As[16 * 264];
    __shared__ float lnb[2][8][16];
    const int tid = threadIdx.x;
    const int lane = tid & 63, w = tid >> 6;          // w in 0..7
    const int l15 = lane & 15, quad = lane >> 4;
    const int r0 = blockIdx.x * 16;
    const int c0w = w * 32;
    short8 wf[8][2];
#pragma unroll
    for (int kc = 0; kc < 8; ++kc)
#pragma unroll
        for (int dt = 0; dt < 2; ++dt)
            wf[kc][dt] = *(const short8*)(WT + (size_t)(c0w + dt * 16 + l15) * DD + kc * 32 + 8 * quad);
    fx4 bb[2], gg[2], ee[2];
#pragma unroll
    for (int dt = 0; dt < 2; ++dt) {
        int col = c0w + dt * 16 + 4 * quad;
        bb[dt] = *(const fx4*)(bias + col);
        gg[dt] = *(const fx4*)(g + col);
        ee[dt] = *(const fx4*)(be + col);
    }
    {   // stage A: 512 threads x 16B
        int row = tid >> 5, c0 = (tid & 31) * 8;
        *(short8*)(As + row * 264 + c0) = *(const short8*)(Ain + (size_t)(r0 + row) * DD + c0);
    }
    __syncthreads();
    fx4 acc[2];
#pragma unroll
    for (int i = 0; i < 2; ++i) acc[i] = (fx4){0.f, 0.f, 0.f, 0.f};
#pragma unroll
    for (int kc = 0; kc < 8; ++kc) {
        short8 a = *(const short8*)(As + l15 * 264 + kc * 32 + 8 * quad);
#pragma unroll
        for (int dt = 0; dt < 2; ++dt)
            acc[dt] = __builtin_amdgcn_mfma_f32_16x16x32_bf16(wf[kc][dt], a, acc[dt], 0, 0, 0);
    }
    // acc[dt][r] = C[r0+l15][c0w+dt*16+4*quad+r]
    const size_t grow = r0 + l15;
    fx4 v4[2];
    float p1 = 0.f, p2 = 0.f;
#pragma unroll
    for (int dt = 0; dt < 2; ++dt) {
        fx4 rv = *(const fx4*)(R + grow * DD + c0w + dt * 16 + 4 * quad);
#pragma unroll
        for (int r = 0; r < 4; ++r) {
            float x = acc[dt][r] + bb[dt][r] + rv[r];
            v4[dt][r] = x; p1 += x; p2 += x * x;
        }
    }
    p1 += __shfl_xor(p1, 16); p2 += __shfl_xor(p2, 16);
    p1 += __shfl_xor(p1, 32); p2 += __shfl_xor(p2, 32);
    if (quad == 0) { lnb[0][w][l15] = p1; lnb[1][w][l15] = p2; }
    __syncthreads();
    float s1 = 0.f, s2 = 0.f;
#pragma unroll
    for (int ww = 0; ww < 8; ++ww) { s1 += lnb[0][ww][l15]; s2 += lnb[1][ww][l15]; }
    const float mean = s1 * (1.0f / 256.0f);
    const float var  = s2 * (1.0f / 256.0f) - mean * mean;
    const float rstd = rsqrtf(var + 1e-5f);
#pragma unroll
    for (int dt = 0; dt < 2; ++dt) {
        fx4 o;
#pragma unroll
        for (int r = 0; r < 4; ++r)
            o[r] = (v4[dt][r] - mean) * rstd * gg[dt][r] + ee[dt][r];
        *(fx4*)(out + grow * DD + c0w + dt * 16 + 4 * quad) = o;
    }
}

// ---------------------------------------------------------------------------
// Flash attention, O^T form, no-max softmax. r15 structure (unchanged):
// Block = 64 q-rows x 512 keys (kq quarter), grid 2048 -> 8 blocks/CU.
// 4 waves = 4 q-subtiles; 16 key-tiles/block from double-buffered,
// XOR-swizzled LDS. Unnormalized partials Od[kq], Lp[kq]; merge in ln_rows.
// ---------------------------------------------------------------------------
__global__ __launch_bounds__(256, 2) void attn_mfma(
        const unsigned short* __restrict__ Qp, const unsigned short* __restrict__ KT,
        const unsigned short* __restrict__ VT2, float* __restrict__ Od,
        float* __restrict__ Lp) {
    __shared__ unsigned short kbuf[2][2048];  // K tile double buffer (4KB ea)
    __shared__ unsigned short vbuf[2][2048];  // V tile double buffer
    __shared__ unsigned int pbuf[4][256];     // per-wave P exchange, pitch 16 dw
    const int tid = threadIdx.x;
    const int lane = tid & 63, w = tid >> 6;  // w = q-subtile
    const int l15 = lane & 15, quad = lane >> 4;
    const int gb = blockIdx.x;                // 0..2047
    const int bh = ((gb & 7) << 1) | ((gb >> 10) & 1);  // XCD-locality swizzle
    const int qc = (gb >> 3) & 31;
    const int kq = (gb >> 8) & 3;                       // key quarter
    const int h  = bh & 3;
    const int b  = bh >> 2;
    const int qrow = qc * 64 + w * 16;
    const int sw = 4 * ((l15 >> 1) & 3);                // pbuf bank swizzle

    short8 aq0, aq1;
    {
        const unsigned short* qptr = Qp + ((size_t)(b * NN + qrow + l15) * DD + h * DHH + 8 * quad);
        aq0 = *(const short8*)qptr;
        aq1 = *(const short8*)(qptr + 32);
    }
    fx4 od0 = (fx4){0.f, 0.f, 0.f, 0.f};
    fx4 od1 = (fx4){0.f, 0.f, 0.f, 0.f};
    fx4 od2 = (fx4){0.f, 0.f, 0.f, 0.f};
    fx4 od3 = (fx4){0.f, 0.f, 0.f, 0.f};
    float lsum = 0.0f;

    unsigned int* pw = &pbuf[w][0];
    const int wcol = (2 * quad) ^ sw;         // write cols (pairs t=2q,2q+1 / +8)
    const int rcol = (4 * quad) ^ sw;         // read col group (t=4Q..4Q+3)
    const unsigned short* ktb = KT  + (size_t)(bh * 64 + kq * 16) * 2048 + tid * 8;
    const unsigned short* vtb = VT2 + (size_t)(bh * 64 + kq * 16) * 2048 + tid * 8;
    // K/V tile swizzle: element e -> e ^ (((e>>6)&3)<<3)  (byte[5:4]^=byte[8:7])
    const int ew = (tid * 8) ^ (((tid >> 3) & 3) << 3);          // stage-write dst
    const int fo = (l15 * 32 + 8 * quad) ^ (((l15 >> 1) & 3) << 3); // frag-read base

    // prologue: stage tile 0 into buffer 0
    {
        uint4v kr = *(const uint4v*)ktb;
        uint4v vr = *(const uint4v*)vtb;
        *(uint4v*)&kbuf[0][ew] = kr;
        *(uint4v*)&vbuf[0][ew] = vr;
    }
    __syncthreads();

    for (int t = 0; t < 16; ++t) {
        const int cur = t & 1;
        const int tn = (t < 15) ? t + 1 : 15;           // clamp (last redundant)
        // issue next-tile global loads FIRST (T14 async split: write after compute)
        uint4v kr = *(const uint4v*)(ktb + (size_t)tn * 2048);
        uint4v vr = *(const uint4v*)(vtb + (size_t)tn * 2048);

        // ---- compute tile t from LDS ----
        const unsigned short* kb = &kbuf[cur][fo];
        short8 ck0 = *(const short8*)(kb);          // keys l15,    d 8q..8q+7
        short8 ck1 = *(const short8*)(kb + 1024);   // keys l15,    d 32+8q..
        short8 ck2 = *(const short8*)(kb + 512);    // keys 16+l15, d 8q..
        short8 ck3 = *(const short8*)(kb + 1536);   // keys 16+l15, d 32+8q..
        const unsigned short* vb = &vbuf[cur][fo];
        short8 cv0 = *(const short8*)(vb);          // d l15,    keys 8q..8q+7
        short8 cv1 = *(const short8*)(vb + 512);    // d 16+l15
        short8 cv2 = *(const short8*)(vb + 1024);   // d 32+l15
        short8 cv3 = *(const short8*)(vb + 1536);   // d 48+l15

        const fx4 z_ = (fx4){0.f, 0.f, 0.f, 0.f};
        fx4 s0 = __builtin_amdgcn_mfma_f32_16x16x32_bf16(ck0, aq0, z_, 0, 0, 0);
        s0     = __builtin_amdgcn_mfma_f32_16x16x32_bf16(ck1, aq1, s0, 0, 0, 0);
        fx4 s1 = __builtin_amdgcn_mfma_f32_16x16x32_bf16(ck2, aq0, z_, 0, 0, 0);
        s1     = __builtin_amdgcn_mfma_f32_16x16x32_bf16(ck3, aq1, s1, 0, 0, 0);
        s0[0] = __expf(s0[0] * 0.125f); s0[1] = __expf(s0[1] * 0.125f);
        s0[2] = __expf(s0[2] * 0.125f); s0[3] = __expf(s0[3] * 0.125f);
        s1[0] = __expf(s1[0] * 0.125f); s1[1] = __expf(s1[1] * 0.125f);
        s1[2] = __expf(s1[2] * 0.125f); s1[3] = __expf(s1[3] * 0.125f);
        lsum += s0[0] + s0[1] + s0[2] + s0[3];
        lsum += s1[0] + s1[1] + s1[2] + s1[3];
        uint2v w1_ = (uint2v){packbf(s0[0], s0[1]), packbf(s0[2], s0[3])};
        uint2v w2_ = (uint2v){packbf(s1[0], s1[1]), packbf(s1[2], s1[3])};
        *(uint2v*)(pw + l15 * 16 + wcol)       = w1_;   // pairs t=2q,2q+1
        *(uint2v*)(pw + l15 * 16 + (wcol ^ 8)) = w2_;   // pairs t=8+2q,8+2q+1
        short8 bp = *(const short8*)(pw + l15 * 16 + rcol);  // keys 8*quad..+7
        od0 = __builtin_amdgcn_mfma_f32_16x16x32_bf16(cv0, bp, od0, 0, 0, 0);
        od1 = __builtin_amdgcn_mfma_f32_16x16x32_bf16(cv1, bp, od1, 0, 0, 0);
        od2 = __builtin_amdgcn_mfma_f32_16x16x32_bf16(cv2, bp, od2, 0, 0, 0);
        od3 = __builtin_amdgcn_mfma_f32_16x16x32_bf16(cv3, bp, od3, 0, 0, 0);

        // ---- land next tile into the other buffer, then sync ----
        *(uint4v*)&kbuf[cur ^ 1][ew] = kr;
        *(uint4v*)&vbuf[cur ^ 1][ew] = vr;
        __syncthreads();
    }

    // per-q partial l (sum over quads); write UNNORMALIZED partials
    lsum += __shfl_xor(lsum, 16);
    lsum += __shfl_xor(lsum, 32);
    const size_t grow = (size_t)(b * NN) + qrow + l15;
    float* obase = Od + (size_t)kq * 2097152 + grow * DD + h * DHH;
    *(fx4*)(obase + 0 * 16 + 4 * quad) = od0;
    *(fx4*)(obase + 1 * 16 + 4 * quad) = od1;
    *(fx4*)(obase + 2 * 16 + 4 * quad) = od2;
    *(fx4*)(obase + 3 * 16 + 4 * quad) = od3;
    if (quad == 0) Lp[(size_t)kq * 32768 + grow * 4 + h] = lsum;
}

// merge kq partials + residual + LayerNorm: Y = LN(sum(od)/sum(l) + Qp)*g+be.
__global__ __launch_bounds__(64) void ln_rows(
        const float* __restrict__ Od, const float* __restrict__ Lp,
        const unsigned short* __restrict__ Qp,
        const float* __restrict__ g, const float* __restrict__ be,
        float* __restrict__ Y) {
    const int lane = threadIdx.x;
    const size_t row = blockIdx.x;
    const int h = lane >> 4;                       // 4 heads x 16 lanes
    fx4 m0 = ((const fx4*)(Od + row * DD))[lane];
    fx4 m1 = ((const fx4*)(Od + 1 * 2097152 + row * DD))[lane];
    fx4 m2 = ((const fx4*)(Od + 2 * 2097152 + row * DD))[lane];
    fx4 m3 = ((const fx4*)(Od + 3 * 2097152 + row * DD))[lane];
    const float inv = 1.0f / (Lp[row * 4 + h] + Lp[32768 + row * 4 + h]
                            + Lp[65536 + row * 4 + h] + Lp[98304 + row * 4 + h]);
    shortx4 qv = ((const shortx4*)(Qp + row * DD))[lane];
    fx4 v;
#pragma unroll
    for (int i = 0; i < 4; ++i)
        v[i] = (m0[i] + m1[i] + m2[i] + m3[i]) * inv + bf2f((unsigned short)qv[i]);
    float s1 = v[0]+v[1]+v[2]+v[3];
    float s2 = v[0]*v[0]+v[1]*v[1]+v[2]*v[2]+v[3]*v[3];
#pragma unroll
    for (int off = 32; off >= 1; off >>= 1) {
        s1 += __shfl_xor(s1, off); s2 += __shfl_xor(s2, off);
    }
    float mean = s1 * (1.0f/256.0f);
    float var  = s2 * (1.0f/256.0f) - mean * mean;
    float rstd = rsqrtf(var + 1e-5f);
    fx4 gv = ((const fx4*)g)[lane];
    fx4 ev = ((const fx4*)be)[lane];
    fx4 o;
#pragma unroll
    for (int i = 0; i < 4; ++i) o[i] = (v[i]-mean)*rstd*gv[i] + ev[i];
    ((fx4*)(Y + row * DD))[lane] = o;
}

extern "C" void kernel_launch(void* const* d_in, const int* in_sizes, int n_in,
                              void* d_out, int out_size, void* d_ws, size_t ws_size,
                              hipStream_t stream) {
    (void)in_sizes; (void)n_in; (void)out_size; (void)ws_size;
    const float* Q     = (const float*)d_in[0];
    const float* K     = (const float*)d_in[1];
    const float* Wq    = (const float*)d_in[2];
    const float* bq    = (const float*)d_in[3];
    const float* Wk    = (const float*)d_in[4];
    const float* bk    = (const float*)d_in[5];
    const float* Wv    = (const float*)d_in[6];
    const float* bv    = (const float*)d_in[7];
    const float* W1    = (const float*)d_in[8];
    const float* b1    = (const float*)d_in[9];
    const float* W2    = (const float*)d_in[10];
    const float* b2    = (const float*)d_in[11];
    const float* g0    = (const float*)d_in[12];
    const float* beta0 = (const float*)d_in[13];
    const float* g1    = (const float*)d_in[14];
    const float* beta1 = (const float*)d_in[15];

    // Workspace: [0,4)Mi Qp bf16 (later H1 bf16); [4,8)Mi Kp (dead after
    // kt_prep -> Lp partials, 512KB); [8,12)Mi Vp (reused as KT);
    // [12,16)Mi VT2; [16,48)Mi Od[4] f32 partials; [48,56)Mi O f32;
    // [56Mi,+640K) WT x5
    char* ws = (char*)d_ws;
    unsigned short* Qp  = (unsigned short*)(ws);
    unsigned short* Kp  = (unsigned short*)(ws + (4u  << 20));
    unsigned short* Vp  = (unsigned short*)(ws + (8u  << 20));
    unsigned short* KT  = Vp;                       // overlays Vp (dead after vt_prep)
    unsigned short* VT2 = (unsigned short*)(ws + (12u << 20));
    float*          Od  = (float*)(ws + (16u << 20));   // 4 x 8MB partials
    float*          O   = (float*)(ws + (48u << 20));
    float*          Lp  = (float*)(ws + (4u << 20));    // overlays Kp (dead)
    unsigned short* WT5 = (unsigned short*)(ws + (56u << 20));
    unsigned short* H1  = Qp;
    float*          out = (float*)d_out;

    const unsigned short* WT1 = WT5 + 3 * 65536;
    const unsigned short* WT2 = WT5 + 4 * 65536;

    const int M = BB * NN;                        // 8192 rows

    wt_prep<<<dim3(4, 4, 5), 256, 0, stream>>>(Wq, Wk, Wv, W1, W2, WT5);
    qkv_mfma<<<dim3(M / 16, 3), 256, 0, stream>>>(Q, K, WT5, bq, bk, bv, Qp, Kp, Vp);
    vt_prep<<<dim3(128, 4), 256, 0, stream>>>(Vp, VT2);
    kt_prep<<<1024, 256, 0, stream>>>(Kp, KT);    // overwrites Vp slot (Vp dead)
    attn_mfma<<<2048, 256, 0, stream>>>(Qp, KT, VT2, Od, Lp);
    ln_rows<<<M, 64, 0, stream>>>(Od, Lp, Qp, g0, beta0, O);
    ffn1_mfma<<<M / 16, 256, 0, stream>>>(O, WT1, b1, H1);
    gemm_ffn2_ln<<<M / 16, 512, 0, stream>>>(H1, WT2, b2, O, g1, beta1, out);
}

// Round 11
// 170.675 us; speedup vs baseline: 1.0548x; 1.0548x over previous
//
#include <hip/hip_runtime.h>

// MAB block, MFMA bf16, round 17: kernel-count reduction 8 -> 5.
// r16 post-mortem: GEMM epilogue vectorization neutral; ledger arithmetic
// shows ~80us of the 180 is inter-kernel dispatch+drain overhead (8 serial
// kernels x ~10us). r17:
//  (a) qkv epilogue writes K directly in KT layout (transposed acc, 4
//      consecutive d contiguous) and V directly in VT2 layout (original
//      operand order, 4 consecutive keys contiguous) -> kt_prep/vt_prep gone.
//  (b) ffn1 fused with the kq-merge + residual + LN (staging phase does
//      Od-sum * 1/l + Qp, 16-thread/row shfl reduce, writes O fp32 for
//      ffn2's residual + bf16 LDS tile) -> ln_rows gone.
// Kernels: wt_prep, qkv_mfma, attn_mfma, ffn1_fused, gemm_ffn2_ln.

typedef float fx4 __attribute__((ext_vector_type(4)));
typedef short short8 __attribute__((ext_vector_type(8)));
typedef short shortx4 __attribute__((ext_vector_type(4)));
typedef unsigned int uint2v __attribute__((ext_vector_type(2)));
typedef unsigned int uint4v __attribute__((ext_vector_type(4)));

#define BB  4
#define NN  2048
#define DD  256
#define HH  4
#define DHH 64

__device__ __forceinline__ float bf2f(unsigned short u) {
    union { unsigned int i; float f; } v; v.i = ((unsigned int)u) << 16; return v.f;
}
__device__ __forceinline__ unsigned short f2bf(float f) {
    union { float f; unsigned int i; } v; v.f = f;
    unsigned int r = v.i + 0x7FFF + ((v.i >> 16) & 1);   // RNE
    return (unsigned short)(r >> 16);
}
__device__ __forceinline__ unsigned int fbits(float f) {
    union { float f; unsigned int i; } v; v.f = f; return v.i;
}
__device__ __forceinline__ unsigned int packbf(float lo, float hi) {
    unsigned int a = fbits(lo), b = fbits(hi);
    a = (a + 0x7FFF + ((a >> 16) & 1)) >> 16;
    b = (b + 0x7FFF + ((b >> 16) & 1)) & 0xFFFF0000u;
    return a | b;
}

// ---------------------------------------------------------------------------
// Weight prep: WT[n][k] = bf16(W[k][n]) for the 5 weight matrices (256x256).
// ---------------------------------------------------------------------------
__global__ __launch_bounds__(256) void wt_prep(
        const float* __restrict__ w0, const float* __restrict__ w1,
        const float* __restrict__ w2, const float* __restrict__ w3,
        const float* __restrict__ w4, unsigned short* __restrict__ dst) {
    __shared__ unsigned short T[64 * 73];
    const int tid = threadIdx.x;
    const int z = blockIdx.z;
    const float* W = (z == 0) ? w0 : (z == 1) ? w1 : (z == 2) ? w2 : (z == 3) ? w3 : w4;
    unsigned short* WT = dst + z * 65536;
    const int nb = blockIdx.x * 64, kb = blockIdx.y * 64;
    {
        int kl = tid >> 2, c0 = (tid & 3) * 16;
        const float* src = W + (size_t)(kb + kl) * DD + nb + c0;
#pragma unroll
        for (int i = 0; i < 16; ++i) T[kl * 73 + c0 + i] = f2bf(src[i]);
    }
    __syncthreads();
    {
        int nl = tid >> 2, k0 = (tid & 3) * 16;
        short8 o0, o1;
#pragma unroll
        for (int i = 0; i < 8; ++i) {
            o0[i] = (short)T[(k0 + i) * 73 + nl];
            o1[i] = (short)T[(k0 + 8 + i) * 73 + nl];
        }
        short8* d = (short8*)(WT + (size_t)(nb + nl) * DD + kb + k0);
        d[0] = o0; d[1] = o1;
    }
}

// ---------------------------------------------------------------------------
// 32-row GEMM body: 4 waves, wave = 32 rows x 32 cols, A fp32 -> bf16 staged.
// LAYOUT 0: row-major C (transposed acc, mfma(wf,a)) -> Qp.
// LAYOUT 1: KT[bh][tile][dhalf][key32][d32] direct (transposed acc).
// LAYOUT 2: VT2[bh][tile][d64][key32] direct (original order, mfma(a,wf)).
// ---------------------------------------------------------------------------
template<int LAYOUT>
__device__ __forceinline__ void gemm32_body(
        const float* __restrict__ Ain, const unsigned short* __restrict__ WT,
        const float* __restrict__ bias, unsigned short* __restrict__ Cout, int bx) {
    __shared__ unsigned short As[32 * 264];
    const int tid = threadIdx.x;
    const int lane = tid & 63, w = tid >> 6;
    const int l15 = lane & 15, quad = lane >> 4;
    const int r0 = (bx >> 1) * 32;
    const int c0w = (bx & 1) * 128 + w * 32;
    short8 wf[8][2];
#pragma unroll
    for (int kc = 0; kc < 8; ++kc)
#pragma unroll
        for (int dt = 0; dt < 2; ++dt)
            wf[kc][dt] = *(const short8*)(WT + (size_t)(c0w + dt * 16 + l15) * DD + kc * 32 + 8 * quad);
    fx4 bb[2];
    float bv[2];
#pragma unroll
    for (int dt = 0; dt < 2; ++dt) {
        if (LAYOUT == 2) bv[dt] = bias[c0w + dt * 16 + l15];
        else             bb[dt] = *(const fx4*)(bias + c0w + dt * 16 + 4 * quad);
    }
    {   // stage A tile (32 x 256) fp32 -> bf16; thread: 32 elems
        int row = tid >> 3, c0 = (tid & 7) * 32;
        short8 o[4];
        const fx4* s4 = (const fx4*)(Ain + (size_t)(r0 + row) * DD + c0);
#pragma unroll
        for (int j = 0; j < 4; ++j) {
            fx4 v0 = s4[2 * j], v1 = s4[2 * j + 1];
#pragma unroll
            for (int i = 0; i < 4; ++i) {
                o[j][i]     = (short)f2bf(v0[i]);
                o[j][i + 4] = (short)f2bf(v1[i]);
            }
        }
        short8* d = (short8*)(As + row * 264 + c0);
#pragma unroll
        for (int j = 0; j < 4; ++j) d[j] = o[j];
    }
    __syncthreads();
    fx4 acc[2][2];
#pragma unroll
    for (int mt = 0; mt < 2; ++mt)
#pragma unroll
        for (int dt = 0; dt < 2; ++dt) acc[mt][dt] = (fx4){0.f, 0.f, 0.f, 0.f};
#pragma unroll
    for (int kc = 0; kc < 8; ++kc) {
        short8 a0 = *(const short8*)(As + l15 * 264 + kc * 32 + 8 * quad);
        short8 a1 = *(const short8*)(As + (16 + l15) * 264 + kc * 32 + 8 * quad);
#pragma unroll
        for (int dt = 0; dt < 2; ++dt) {
            if (LAYOUT == 2) {
                acc[0][dt] = __builtin_amdgcn_mfma_f32_16x16x32_bf16(a0, wf[kc][dt], acc[0][dt], 0, 0, 0);
                acc[1][dt] = __builtin_amdgcn_mfma_f32_16x16x32_bf16(a1, wf[kc][dt], acc[1][dt], 0, 0, 0);
            } else {
                acc[0][dt] = __builtin_amdgcn_mfma_f32_16x16x32_bf16(wf[kc][dt], a0, acc[0][dt], 0, 0, 0);
                acc[1][dt] = __builtin_amdgcn_mfma_f32_16x16x32_bf16(wf[kc][dt], a1, acc[1][dt], 0, 0, 0);
            }
        }
    }
    if (LAYOUT == 0) {
        // acc[mt][dt][r] = C[r0+mt*16+l15][c0w+dt*16+4*quad+r]
#pragma unroll
        for (int mt = 0; mt < 2; ++mt) {
            const size_t grow = r0 + mt * 16 + l15;
#pragma unroll
            for (int dt = 0; dt < 2; ++dt) {
                shortx4 pk;
#pragma unroll
                for (int r = 0; r < 4; ++r) pk[r] = (short)f2bf(acc[mt][dt][r] + bb[dt][r]);
                *(shortx4*)(Cout + grow * DD + c0w + dt * 16 + 4 * quad) = pk;
            }
        }
    } else if (LAYOUT == 1) {
        // KT: col = c0w+dt*16+4*quad+r (d dim), key = r0+mt*16+l15
        const int tl = (r0 & 2047) >> 5;
        const int b  = r0 >> 11;
#pragma unroll
        for (int mt = 0; mt < 2; ++mt) {
            const int key32 = mt * 16 + l15;
#pragma unroll
            for (int dt = 0; dt < 2; ++dt) {
                const int col = c0w + dt * 16 + 4 * quad;
                shortx4 pk;
#pragma unroll
                for (int r = 0; r < 4; ++r) pk[r] = (short)f2bf(acc[mt][dt][r] + bb[dt][r]);
                unsigned short* dstp = Cout
                    + ((size_t)((b * 4 + (col >> 6)) * 64 + tl)) * 2048
                    + ((col >> 5) & 1) * 1024 + key32 * 32 + (col & 31);
                *(shortx4*)dstp = pk;
            }
        }
    } else {
        // VT2: key = r0+mt*16+4*quad+r, col = c0w+dt*16+l15 (d dim)
        const int tl = (r0 & 2047) >> 5;
        const int b  = r0 >> 11;
#pragma unroll
        for (int mt = 0; mt < 2; ++mt) {
#pragma unroll
            for (int dt = 0; dt < 2; ++dt) {
                const int col = c0w + dt * 16 + l15;
                shortx4 pk;
#pragma unroll
                for (int r = 0; r < 4; ++r) pk[r] = (short)f2bf(acc[mt][dt][r] + bv[dt]);
                unsigned short* dstp = Cout
                    + ((size_t)((b * 4 + (col >> 6)) * 64 + tl)) * 2048
                    + (col & 63) * 32 + mt * 16 + 4 * quad;
                *(shortx4*)dstp = pk;
            }
        }
    }
}

// Fused QKV projections: grid (512, 3); y selects {Q->Qp, K->KT, K->VT2}.
__global__ __launch_bounds__(256, 4) void qkv_mfma(
        const float* __restrict__ Q, const float* __restrict__ K,
        const unsigned short* __restrict__ WT5,
        const float* __restrict__ bq, const float* __restrict__ bk,
        const float* __restrict__ bv,
        unsigned short* __restrict__ Qp, unsigned short* __restrict__ KT,
        unsigned short* __restrict__ VT2) {
    const int z = blockIdx.y;
    if (z == 0)      gemm32_body<0>(Q, WT5,           bq, Qp,  blockIdx.x);
    else if (z == 1) gemm32_body<1>(K, WT5 + 65536,   bk, KT,  blockIdx.x);
    else             gemm32_body<2>(K, WT5 + 131072,  bv, VT2, blockIdx.x);
}

// ---------------------------------------------------------------------------
// Flash attention, O^T form, no-max softmax. r15 structure (unchanged):
// Block = 64 q-rows x 512 keys (kq quarter), grid 2048 -> 8 blocks/CU.
// 4 waves = 4 q-subtiles; 16 key-tiles/block from double-buffered,
// XOR-swizzled LDS. Unnormalized partials Od[kq], Lp[kq]; merge in ffn1.
// ---------------------------------------------------------------------------
__global__ __launch_bounds__(256, 2) void attn_mfma(
        const unsigned short* __restrict__ Qp, const unsigned short* __restrict__ KT,
        const unsigned short* __restrict__ VT2, float* __restrict__ Od,
        float* __restrict__ Lp) {
    __shared__ unsigned short kbuf[2][2048];  // K tile double buffer (4KB ea)
    __shared__ unsigned short vbuf[2][2048];  // V tile double buffer
    __shared__ unsigned int pbuf[4][256];     // per-wave P exchange, pitch 16 dw
    const int tid = threadIdx.x;
    const int lane = tid & 63, w = tid >> 6;  // w = q-subtile
    const int l15 = lane & 15, quad = lane >> 4;
    const int gb = blockIdx.x;                // 0..2047
    const int bh = ((gb & 7) << 1) | ((gb >> 10) & 1);  // XCD-locality swizzle
    const int qc = (gb >> 3) & 31;
    const int kq = (gb >> 8) & 3;                       // key quarter
    const int h  = bh & 3;
    const int b  = bh >> 2;
    const int qrow = qc * 64 + w * 16;
    const int sw = 4 * ((l15 >> 1) & 3);                // pbuf bank swizzle

    short8 aq0, aq1;
    {
        const unsigned short* qptr = Qp + ((size_t)(b * NN + qrow + l15) * DD + h * DHH + 8 * quad);
        aq0 = *(const short8*)qptr;
        aq1 = *(const short8*)(qptr + 32);
    }
    fx4 od0 = (fx4){0.f, 0.f, 0.f, 0.f};
    fx4 od1 = (fx4){0.f, 0.f, 0.f, 0.f};
    fx4 od2 = (fx4){0.f, 0.f, 0.f, 0.f};
    fx4 od3 = (fx4){0.f, 0.f, 0.f, 0.f};
    float lsum = 0.0f;

    unsigned int* pw = &pbuf[w][0];
    const int wcol = (2 * quad) ^ sw;         // write cols (pairs t=2q,2q+1 / +8)
    const int rcol = (4 * quad) ^ sw;         // read col group (t=4Q..4Q+3)
    const unsigned short* ktb = KT  + (size_t)(bh * 64 + kq * 16) * 2048 + tid * 8;
    const unsigned short* vtb = VT2 + (size_t)(bh * 64 + kq * 16) * 2048 + tid * 8;
    // K/V tile swizzle: element e -> e ^ (((e>>6)&3)<<3)  (byte[5:4]^=byte[8:7])
    const int ew = (tid * 8) ^ (((tid >> 3) & 3) << 3);          // stage-write dst
    const int fo = (l15 * 32 + 8 * quad) ^ (((l15 >> 1) & 3) << 3); // frag-read base

    // prologue: stage tile 0 into buffer 0
    {
        uint4v kr = *(const uint4v*)ktb;
        uint4v vr = *(const uint4v*)vtb;
        *(uint4v*)&kbuf[0][ew] = kr;
        *(uint4v*)&vbuf[0][ew] = vr;
    }
    __syncthreads();

    for (int t = 0; t < 16; ++t) {
        const int cur = t & 1;
        const int tn = (t < 15) ? t + 1 : 15;           // clamp (last redundant)
        // issue next-tile global loads FIRST (T14 async split: write after compute)
        uint4v kr = *(const uint4v*)(ktb + (size_t)tn * 2048);
        uint4v vr = *(const uint4v*)(vtb + (size_t)tn * 2048);

        // ---- compute tile t from LDS ----
        const unsigned short* kb = &kbuf[cur][fo];
        short8 ck0 = *(const short8*)(kb);          // keys l15,    d 8q..8q+7
        short8 ck1 = *(const short8*)(kb + 1024);   // keys l15,    d 32+8q..
        short8 ck2 = *(const short8*)(kb + 512);    // keys 16+l15, d 8q..
        short8 ck3 = *(const short8*)(kb + 1536);   // keys 16+l15, d 32+8q..
        const unsigned short* vb = &vbuf[cur][fo];
        short8 cv0 = *(const short8*)(vb);          // d l15,    keys 8q..8q+7
        short8 cv1 = *(const short8*)(vb + 512);    // d 16+l15
        short8 cv2 = *(const short8*)(vb + 1024);   // d 32+l15
        short8 cv3 = *(const short8*)(vb + 1536);   // d 48+l15

        const fx4 z_ = (fx4){0.f, 0.f, 0.f, 0.f};
        fx4 s0 = __builtin_amdgcn_mfma_f32_16x16x32_bf16(ck0, aq0, z_, 0, 0, 0);
        s0     = __builtin_amdgcn_mfma_f32_16x16x32_bf16(ck1, aq1, s0, 0, 0, 0);
        fx4 s1 = __builtin_amdgcn_mfma_f32_16x16x32_bf16(ck2, aq0, z_, 0, 0, 0);
        s1     = __builtin_amdgcn_mfma_f32_16x16x32_bf16(ck3, aq1, s1, 0, 0, 0);
        s0[0] = __expf(s0[0] * 0.125f); s0[1] = __expf(s0[1] * 0.125f);
        s0[2] = __expf(s0[2] * 0.125f); s0[3] = __expf(s0[3] * 0.125f);
        s1[0] = __expf(s1[0] * 0.125f); s1[1] = __expf(s1[1] * 0.125f);
        s1[2] = __expf(s1[2] * 0.125f); s1[3] = __expf(s1[3] * 0.125f);
        lsum += s0[0] + s0[1] + s0[2] + s0[3];
        lsum += s1[0] + s1[1] + s1[2] + s1[3];
        uint2v w1_ = (uint2v){packbf(s0[0], s0[1]), packbf(s0[2], s0[3])};
        uint2v w2_ = (uint2v){packbf(s1[0], s1[1]), packbf(s1[2], s1[3])};
        *(uint2v*)(pw + l15 * 16 + wcol)       = w1_;   // pairs t=2q,2q+1
        *(uint2v*)(pw + l15 * 16 + (wcol ^ 8)) = w2_;   // pairs t=8+2q,8+2q+1
        short8 bp = *(const short8*)(pw + l15 * 16 + rcol);  // keys 8*quad..+7
        od0 = __builtin_amdgcn_mfma_f32_16x16x32_bf16(cv0, bp, od0, 0, 0, 0);
        od1 = __builtin_amdgcn_mfma_f32_16x16x32_bf16(cv1, bp, od1, 0, 0, 0);
        od2 = __builtin_amdgcn_mfma_f32_16x16x32_bf16(cv2, bp, od2, 0, 0, 0);
        od3 = __builtin_amdgcn_mfma_f32_16x16x32_bf16(cv3, bp, od3, 0, 0, 0);

        // ---- land next tile into the other buffer, then sync ----
        *(uint4v*)&kbuf[cur ^ 1][ew] = kr;
        *(uint4v*)&vbuf[cur ^ 1][ew] = vr;
        __syncthreads();
    }

    // per-q partial l (sum over quads); write UNNORMALIZED partials
    lsum += __shfl_xor(lsum, 16);
    lsum += __shfl_xor(lsum, 32);
    const size_t grow = (size_t)(b * NN) + qrow + l15;
    float* obase = Od + (size_t)kq * 2097152 + grow * DD + h * DHH;
    *(fx4*)(obase + 0 * 16 + 4 * quad) = od0;
    *(fx4*)(obase + 1 * 16 + 4 * quad) = od1;
    *(fx4*)(obase + 2 * 16 + 4 * quad) = od2;
    *(fx4*)(obase + 3 * 16 + 4 * quad) = od3;
    if (quad == 0) Lp[(size_t)kq * 32768 + grow * 4 + h] = lsum;
}

// ---------------------------------------------------------------------------
// FFN1 fused with attn merge + residual + LayerNorm:
//   O = LN(sum_kq(Od)/sum_kq(Lp) + Qp) * g0 + beta0   (fp32, for ffn2's R)
//   H1 = relu(O @ W1 + b1)                             (bf16)
// Block = 32 rows x 256 cols, 8 waves (512 thr). Staging: 16 thr/row, 16
// elems each; LN row-reduce via shfl_xor 1/2/4/8.
// ---------------------------------------------------------------------------
__global__ __launch_bounds__(512) void ffn1_fused(
        const float* __restrict__ Od, const float* __restrict__ Lp,
        const unsigned short* __restrict__ Qp,
        const float* __restrict__ g, const float* __restrict__ be,
        const unsigned short* __restrict__ WT1, const float* __restrict__ b1,
        float* __restrict__ O, unsigned short* __restrict__ H1) {
    __shared__ unsigned short As[32 * 264];
    const int tid = threadIdx.x;
    const int lane = tid & 63, w = tid >> 6;          // w in 0..7
    const int l15 = lane & 15, quad = lane >> 4;
    const int r0 = blockIdx.x * 32;
    const int c0w = w * 32;
    {   // ---- merge + residual + LN staging: row = tid>>4, 16 elems ----
        const int row = tid >> 4, c0 = (tid & 15) * 16;
        const size_t grow = r0 + row;
        const int hh = c0 >> 6;
        const float inv = 1.0f / (Lp[grow * 4 + hh] + Lp[32768 + grow * 4 + hh]
                                + Lp[65536 + grow * 4 + hh] + Lp[98304 + grow * 4 + hh]);
        float v[16];
        float s1 = 0.f, s2 = 0.f;
        const float* odp = Od + grow * DD + c0;
#pragma unroll
        for (int j = 0; j < 4; ++j) {
            fx4 m0 = *(const fx4*)(odp + j * 4);
            fx4 m1 = *(const fx4*)(odp + 2097152 + j * 4);
            fx4 m2 = *(const fx4*)(odp + 4194304 + j * 4);
            fx4 m3 = *(const fx4*)(odp + 6291456 + j * 4);
            shortx4 qv = *(const shortx4*)(Qp + grow * DD + c0 + j * 4);
#pragma unroll
            for (int i = 0; i < 4; ++i) {
                float x = (m0[i] + m1[i] + m2[i] + m3[i]) * inv
                        + bf2f((unsigned short)qv[i]);
                v[j * 4 + i] = x; s1 += x; s2 += x * x;
            }
        }
        s1 += __shfl_xor(s1, 1); s2 += __shfl_xor(s2, 1);
        s1 += __shfl_xor(s1, 2); s2 += __shfl_xor(s2, 2);
        s1 += __shfl_xor(s1, 4); s2 += __shfl_xor(s2, 4);
        s1 += __shfl_xor(s1, 8); s2 += __shfl_xor(s2, 8);
        const float mean = s1 * (1.0f / 256.0f);
        const float var  = s2 * (1.0f / 256.0f) - mean * mean;
        const float rstd = rsqrtf(var + 1e-5f);
#pragma unroll
        for (int j = 0; j < 4; ++j) {
            fx4 gg = *(const fx4*)(g + c0 + j * 4);
            fx4 ee = *(const fx4*)(be + c0 + j * 4);
            fx4 o; shortx4 ob;
#pragma unroll
            for (int i = 0; i < 4; ++i) {
                o[i] = (v[j * 4 + i] - mean) * rstd * gg[i] + ee[i];
                ob[i] = (short)f2bf(o[i]);
            }
            *(fx4*)(O + grow * DD + c0 + j * 4) = o;
            *(shortx4*)(As + row * 264 + c0 + j * 4) = ob;
        }
    }
    // W frags + bias (after staging to limit live pressure)
    short8 wf[8][2];
#pragma unroll
    for (int kc = 0; kc < 8; ++kc)
#pragma unroll
        for (int dt = 0; dt < 2; ++dt)
            wf[kc][dt] = *(const short8*)(WT1 + (size_t)(c0w + dt * 16 + l15) * DD + kc * 32 + 8 * quad);
    fx4 bb[2];
#pragma unroll
    for (int dt = 0; dt < 2; ++dt)
        bb[dt] = *(const fx4*)(b1 + c0w + dt * 16 + 4 * quad);
    __syncthreads();
    fx4 acc[2][2];
#pragma unroll
    for (int mt = 0; mt < 2; ++mt)
#pragma unroll
        for (int dt = 0; dt < 2; ++dt) acc[mt][dt] = (fx4){0.f, 0.f, 0.f, 0.f};
#pragma unroll
    for (int kc = 0; kc < 8; ++kc) {
        short8 a0 = *(const short8*)(As + l15 * 264 + kc * 32 + 8 * quad);
        short8 a1 = *(const short8*)(As + (16 + l15) * 264 + kc * 32 + 8 * quad);
#pragma unroll
        for (int dt = 0; dt < 2; ++dt) {
            acc[0][dt] = __builtin_amdgcn_mfma_f32_16x16x32_bf16(wf[kc][dt], a0, acc[0][dt], 0, 0, 0);
            acc[1][dt] = __builtin_amdgcn_mfma_f32_16x16x32_bf16(wf[kc][dt], a1, acc[1][dt], 0, 0, 0);
        }
    }
#pragma unroll
    for (int mt = 0; mt < 2; ++mt) {
        const size_t grow = r0 + mt * 16 + l15;
#pragma unroll
        for (int dt = 0; dt < 2; ++dt) {
            shortx4 pk;
#pragma unroll
            for (int r = 0; r < 4; ++r)
                pk[r] = (short)f2bf(fmaxf(acc[mt][dt][r] + bb[dt][r], 0.0f));
            *(shortx4*)(H1 + grow * DD + c0w + dt * 16 + 4 * quad) = pk;
        }
    }
}

// ---------------------------------------------------------------------------
// FFN2 + residual + LayerNorm fused: out = LN(R + A@W2 + b2), fp32 out.
// Block = 16 rows x 256 cols, 8 waves (wave = 16x32). r16 transposed-acc form.
// ---------------------------------------------------------------------------
__global__ __launch_bounds__(512, 4) void gemm_ffn2_ln(
        const unsigned short* __restrict__ Ain, const unsigned short* __restrict__ WT,
        const float* __restrict__ bias, const float* __restrict__ R,
        const float* __restrict__ g, const float* __restrict__ be,
        float* __restrict__ out) {
    __shared__ unsigned short As[16 * 264];
    __shared__ float lnb[2][8][16];
    const int tid = threadIdx.x;
    const int lane = tid & 63, w = tid >> 6;          // w in 0..7
    const int l15 = lane & 15, quad = lane >> 4;
    const int r0 = blockIdx.x * 16;
    const int c0w = w * 32;
    short8 wf[8][2];
#pragma unroll
    for (int kc = 0; kc < 8; ++kc)
#pragma unroll
        for (int dt = 0; dt < 2; ++dt)
            wf[kc][dt] = *(const short8*)(WT + (size_t)(c0w + dt * 16 + l15) * DD + kc * 32 + 8 * quad);
    fx4 bb[2], gg[2], ee[2];
#pragma unroll
    for (int dt = 0; dt < 2; ++dt) {
        int col = c0w + dt * 16 + 4 * quad;
        bb[dt] = *(const fx4*)(bias + col);
        gg[dt] = *(const fx4*)(g + col);
        ee[dt] = *(const fx4*)(be + col);
    }
    {   // stage A: 512 threads x 16B
        int row = tid >> 5, c0 = (tid & 31) * 8;
        *(short8*)(As + row * 264 + c0) = *(const short8*)(Ain + (size_t)(r0 + row) * DD + c0);
    }
    __syncthreads();
    fx4 acc[2];
#pragma unroll
    for (int i = 0; i < 2; ++i) acc[i] = (fx4){0.f, 0.f, 0.f, 0.f};
#pragma unroll
    for (int kc = 0; kc < 8; ++kc) {
        short8 a = *(const short8*)(As + l15 * 264 + kc * 32 + 8 * quad);
#pragma unroll
        for (int dt = 0; dt < 2; ++dt)
            acc[dt] = __builtin_amdgcn_mfma_f32_16x16x32_bf16(wf[kc][dt], a, acc[dt], 0, 0, 0);
    }
    // acc[dt][r] = C[r0+l15][c0w+dt*16+4*quad+r]
    const size_t grow = r0 + l15;
    fx4 v4[2];
    float p1 = 0.f, p2 = 0.f;
#pragma unroll
    for (int dt = 0; dt < 2; ++dt) {
        fx4 rv = *(const fx4*)(R + grow * DD + c0w + dt * 16 + 4 * quad);
#pragma unroll
        for (int r = 0; r < 4; ++r) {
            float x = acc[dt][r] + bb[dt][r] + rv[r];
            v4[dt][r] = x; p1 += x; p2 += x * x;
        }
    }
    p1 += __shfl_xor(p1, 16); p2 += __shfl_xor(p2, 16);
    p1 += __shfl_xor(p1, 32); p2 += __shfl_xor(p2, 32);
    if (quad == 0) { lnb[0][w][l15] = p1; lnb[1][w][l15] = p2; }
    __syncthreads();
    float s1 = 0.f, s2 = 0.f;
#pragma unroll
    for (int ww = 0; ww < 8; ++ww) { s1 += lnb[0][ww][l15]; s2 += lnb[1][ww][l15]; }
    const float mean = s1 * (1.0f / 256.0f);
    const float var  = s2 * (1.0f / 256.0f) - mean * mean;
    const float rstd = rsqrtf(var + 1e-5f);
#pragma unroll
    for (int dt = 0; dt < 2; ++dt) {
        fx4 o;
#pragma unroll
        for (int r = 0; r < 4; ++r)
            o[r] = (v4[dt][r] - mean) * rstd * gg[dt][r] + ee[dt][r];
        *(fx4*)(out + grow * DD + c0w + dt * 16 + 4 * quad) = o;
    }
}

extern "C" void kernel_launch(void* const* d_in, const int* in_sizes, int n_in,
                              void* d_out, int out_size, void* d_ws, size_t ws_size,
                              hipStream_t stream) {
    (void)in_sizes; (void)n_in; (void)out_size; (void)ws_size;
    const float* Q     = (const float*)d_in[0];
    const float* K     = (const float*)d_in[1];
    const float* Wq    = (const float*)d_in[2];
    const float* bq    = (const float*)d_in[3];
    const float* Wk    = (const float*)d_in[4];
    const float* bk    = (const float*)d_in[5];
    const float* Wv    = (const float*)d_in[6];
    const float* bv    = (const float*)d_in[7];
    const float* W1    = (const float*)d_in[8];
    const float* b1    = (const float*)d_in[9];
    const float* W2    = (const float*)d_in[10];
    const float* b2    = (const float*)d_in[11];
    const float* g0    = (const float*)d_in[12];
    const float* beta0 = (const float*)d_in[13];
    const float* g1    = (const float*)d_in[14];
    const float* beta1 = (const float*)d_in[15];

    // Workspace: [0,4)Mi Qp bf16 (later H1 bf16); [4,8)Mi KT; [8,12)Mi VT2;
    // [12,44)Mi Od[4] f32; [44,52)Mi O f32; [52,+512K) Lp; [53Mi,+640K) WT x5
    char* ws = (char*)d_ws;
    unsigned short* Qp  = (unsigned short*)(ws);
    unsigned short* KT  = (unsigned short*)(ws + (4u  << 20));
    unsigned short* VT2 = (unsigned short*)(ws + (8u  << 20));
    float*          Od  = (float*)(ws + (12u << 20));   // 4 x 8MB partials
    float*          O   = (float*)(ws + (44u << 20));
    float*          Lp  = (float*)(ws + (52u << 20));
    unsigned short* WT5 = (unsigned short*)(ws + (53u << 20));
    unsigned short* H1  = Qp;
    float*          out = (float*)d_out;

    const unsigned short* WT1 = WT5 + 3 * 65536;
    const unsigned short* WT2 = WT5 + 4 * 65536;

    const int M = BB * NN;                        // 8192 rows

    wt_prep<<<dim3(4, 4, 5), 256, 0, stream>>>(Wq, Wk, Wv, W1, W2, WT5);
    qkv_mfma<<<dim3(M / 16, 3), 256, 0, stream>>>(Q, K, WT5, bq, bk, bv, Qp, KT, VT2);
    attn_mfma<<<2048, 256, 0, stream>>>(Qp, KT, VT2, Od, Lp);
    ffn1_fused<<<M / 32, 512, 0, stream>>>(Od, Lp, Qp, g0, beta0, WT1, b1, O, H1);
    gemm_ffn2_ln<<<M / 16, 512, 0, stream>>>(H1, WT2, b2, O, g1, beta1, out);
}

// Round 12
// 164.817 us; speedup vs baseline: 1.0923x; 1.0355x over previous
//
#include <hip/hip_runtime.h>

// MAB block, MFMA bf16, round 18: fuse ffn1+ffn2 -> 4 kernels.
// r17 post-mortem: kernel-count cut 8->5 gave -9.3us (~3us/launch+drain +
// removed traffic). ffn1/ffn2 dependency is row-wise only -> fuse:
// block = 32 rows, 512 thr; phase1 merge+residual+LN -> As bf16 + O fp32
// (global, L2-resident, for phase-3 residual); phase2 ffn1 MFMA -> relu ->
// Hs (LDS, H1 never global); phase3 ffn2 MFMA -> +b2+O -> row-LN -> out.
// Saves H1 round-trip (8MB) + 1 launch/drain. qkv/attn unchanged from r17.

typedef float fx4 __attribute__((ext_vector_type(4)));
typedef short short8 __attribute__((ext_vector_type(8)));
typedef short shortx4 __attribute__((ext_vector_type(4)));
typedef unsigned int uint2v __attribute__((ext_vector_type(2)));
typedef unsigned int uint4v __attribute__((ext_vector_type(4)));

#define BB  4
#define NN  2048
#define DD  256
#define HH  4
#define DHH 64

__device__ __forceinline__ float bf2f(unsigned short u) {
    union { unsigned int i; float f; } v; v.i = ((unsigned int)u) << 16; return v.f;
}
__device__ __forceinline__ unsigned short f2bf(float f) {
    union { float f; unsigned int i; } v; v.f = f;
    unsigned int r = v.i + 0x7FFF + ((v.i >> 16) & 1);   // RNE
    return (unsigned short)(r >> 16);
}
__device__ __forceinline__ unsigned int fbits(float f) {
    union { float f; unsigned int i; } v; v.f = f; return v.i;
}
__device__ __forceinline__ unsigned int packbf(float lo, float hi) {
    unsigned int a = fbits(lo), b = fbits(hi);
    a = (a + 0x7FFF + ((a >> 16) & 1)) >> 16;
    b = (b + 0x7FFF + ((b >> 16) & 1)) & 0xFFFF0000u;
    return a | b;
}

// ---------------------------------------------------------------------------
// Weight prep: WT[n][k] = bf16(W[k][n]) for the 5 weight matrices (256x256).
// ---------------------------------------------------------------------------
__global__ __launch_bounds__(256) void wt_prep(
        const float* __restrict__ w0, const float* __restrict__ w1,
        const float* __restrict__ w2, const float* __restrict__ w3,
        const float* __restrict__ w4, unsigned short* __restrict__ dst) {
    __shared__ unsigned short T[64 * 73];
    const int tid = threadIdx.x;
    const int z = blockIdx.z;
    const float* W = (z == 0) ? w0 : (z == 1) ? w1 : (z == 2) ? w2 : (z == 3) ? w3 : w4;
    unsigned short* WT = dst + z * 65536;
    const int nb = blockIdx.x * 64, kb = blockIdx.y * 64;
    {
        int kl = tid >> 2, c0 = (tid & 3) * 16;
        const float* src = W + (size_t)(kb + kl) * DD + nb + c0;
#pragma unroll
        for (int i = 0; i < 16; ++i) T[kl * 73 + c0 + i] = f2bf(src[i]);
    }
    __syncthreads();
    {
        int nl = tid >> 2, k0 = (tid & 3) * 16;
        short8 o0, o1;
#pragma unroll
        for (int i = 0; i < 8; ++i) {
            o0[i] = (short)T[(k0 + i) * 73 + nl];
            o1[i] = (short)T[(k0 + 8 + i) * 73 + nl];
        }
        short8* d = (short8*)(WT + (size_t)(nb + nl) * DD + kb + k0);
        d[0] = o0; d[1] = o1;
    }
}

// ---------------------------------------------------------------------------
// 32-row GEMM body: 4 waves, wave = 32 rows x 32 cols, A fp32 -> bf16 staged.
// LAYOUT 0: row-major C (transposed acc, mfma(wf,a)) -> Qp.
// LAYOUT 1: KT[bh][tile][dhalf][key32][d32] direct (transposed acc).
// LAYOUT 2: VT2[bh][tile][d64][key32] direct (original order, mfma(a,wf)).
// ---------------------------------------------------------------------------
template<int LAYOUT>
__device__ __forceinline__ void gemm32_body(
        const float* __restrict__ Ain, const unsigned short* __restrict__ WT,
        const float* __restrict__ bias, unsigned short* __restrict__ Cout, int bx) {
    __shared__ unsigned short As[32 * 264];
    const int tid = threadIdx.x;
    const int lane = tid & 63, w = tid >> 6;
    const int l15 = lane & 15, quad = lane >> 4;
    const int r0 = (bx >> 1) * 32;
    const int c0w = (bx & 1) * 128 + w * 32;
    short8 wf[8][2];
#pragma unroll
    for (int kc = 0; kc < 8; ++kc)
#pragma unroll
        for (int dt = 0; dt < 2; ++dt)
            wf[kc][dt] = *(const short8*)(WT + (size_t)(c0w + dt * 16 + l15) * DD + kc * 32 + 8 * quad);
    fx4 bb[2];
    float bv[2];
#pragma unroll
    for (int dt = 0; dt < 2; ++dt) {
        if (LAYOUT == 2) bv[dt] = bias[c0w + dt * 16 + l15];
        else             bb[dt] = *(const fx4*)(bias + c0w + dt * 16 + 4 * quad);
    }
    {   // stage A tile (32 x 256) fp32 -> bf16; thread: 32 elems
        int row = tid >> 3, c0 = (tid & 7) * 32;
        short8 o[4];
        const fx4* s4 = (const fx4*)(Ain + (size_t)(r0 + row) * DD + c0);
#pragma unroll
        for (int j = 0; j < 4; ++j) {
            fx4 v0 = s4[2 * j], v1 = s4[2 * j + 1];
#pragma unroll
            for (int i = 0; i < 4; ++i) {
                o[j][i]     = (short)f2bf(v0[i]);
                o[j][i + 4] = (short)f2bf(v1[i]);
            }
        }
        short8* d = (short8*)(As + row * 264 + c0);
#pragma unroll
        for (int j = 0; j < 4; ++j) d[j] = o[j];
    }
    __syncthreads();
    fx4 acc[2][2];
#pragma unroll
    for (int mt = 0; mt < 2; ++mt)
#pragma unroll
        for (int dt = 0; dt < 2; ++dt) acc[mt][dt] = (fx4){0.f, 0.f, 0.f, 0.f};
#pragma unroll
    for (int kc = 0; kc < 8; ++kc) {
        short8 a0 = *(const short8*)(As + l15 * 264 + kc * 32 + 8 * quad);
        short8 a1 = *(const short8*)(As + (16 + l15) * 264 + kc * 32 + 8 * quad);
#pragma unroll
        for (int dt = 0; dt < 2; ++dt) {
            if (LAYOUT == 2) {
                acc[0][dt] = __builtin_amdgcn_mfma_f32_16x16x32_bf16(a0, wf[kc][dt], acc[0][dt], 0, 0, 0);
                acc[1][dt] = __builtin_amdgcn_mfma_f32_16x16x32_bf16(a1, wf[kc][dt], acc[1][dt], 0, 0, 0);
            } else {
                acc[0][dt] = __builtin_amdgcn_mfma_f32_16x16x32_bf16(wf[kc][dt], a0, acc[0][dt], 0, 0, 0);
                acc[1][dt] = __builtin_amdgcn_mfma_f32_16x16x32_bf16(wf[kc][dt], a1, acc[1][dt], 0, 0, 0);
            }
        }
    }
    if (LAYOUT == 0) {
        // acc[mt][dt][r] = C[r0+mt*16+l15][c0w+dt*16+4*quad+r]
#pragma unroll
        for (int mt = 0; mt < 2; ++mt) {
            const size_t grow = r0 + mt * 16 + l15;
#pragma unroll
            for (int dt = 0; dt < 2; ++dt) {
                shortx4 pk;
#pragma unroll
                for (int r = 0; r < 4; ++r) pk[r] = (short)f2bf(acc[mt][dt][r] + bb[dt][r]);
                *(shortx4*)(Cout + grow * DD + c0w + dt * 16 + 4 * quad) = pk;
            }
        }
    } else if (LAYOUT == 1) {
        // KT: col = c0w+dt*16+4*quad+r (d dim), key = r0+mt*16+l15
        const int tl = (r0 & 2047) >> 5;
        const int b  = r0 >> 11;
#pragma unroll
        for (int mt = 0; mt < 2; ++mt) {
            const int key32 = mt * 16 + l15;
#pragma unroll
            for (int dt = 0; dt < 2; ++dt) {
                const int col = c0w + dt * 16 + 4 * quad;
                shortx4 pk;
#pragma unroll
                for (int r = 0; r < 4; ++r) pk[r] = (short)f2bf(acc[mt][dt][r] + bb[dt][r]);
                unsigned short* dstp = Cout
                    + ((size_t)((b * 4 + (col >> 6)) * 64 + tl)) * 2048
                    + ((col >> 5) & 1) * 1024 + key32 * 32 + (col & 31);
                *(shortx4*)dstp = pk;
            }
        }
    } else {
        // VT2: key = r0+mt*16+4*quad+r, col = c0w+dt*16+l15 (d dim)
        const int tl = (r0 & 2047) >> 5;
        const int b  = r0 >> 11;
#pragma unroll
        for (int mt = 0; mt < 2; ++mt) {
#pragma unroll
            for (int dt = 0; dt < 2; ++dt) {
                const int col = c0w + dt * 16 + l15;
                shortx4 pk;
#pragma unroll
                for (int r = 0; r < 4; ++r) pk[r] = (short)f2bf(acc[mt][dt][r] + bv[dt]);
                unsigned short* dstp = Cout
                    + ((size_t)((b * 4 + (col >> 6)) * 64 + tl)) * 2048
                    + (col & 63) * 32 + mt * 16 + 4 * quad;
                *(shortx4*)dstp = pk;
            }
        }
    }
}

// Fused QKV projections: grid (512, 3); y selects {Q->Qp, K->KT, K->VT2}.
__global__ __launch_bounds__(256, 4) void qkv_mfma(
        const float* __restrict__ Q, const float* __restrict__ K,
        const unsigned short* __restrict__ WT5,
        const float* __restrict__ bq, const float* __restrict__ bk,
        const float* __restrict__ bv,
        unsigned short* __restrict__ Qp, unsigned short* __restrict__ KT,
        unsigned short* __restrict__ VT2) {
    const int z = blockIdx.y;
    if (z == 0)      gemm32_body<0>(Q, WT5,           bq, Qp,  blockIdx.x);
    else if (z == 1) gemm32_body<1>(K, WT5 + 65536,   bk, KT,  blockIdx.x);
    else             gemm32_body<2>(K, WT5 + 131072,  bv, VT2, blockIdx.x);
}

// ---------------------------------------------------------------------------
// Flash attention, O^T form, no-max softmax. r15 structure (unchanged):
// Block = 64 q-rows x 512 keys (kq quarter), grid 2048 -> 8 blocks/CU.
// 4 waves = 4 q-subtiles; 16 key-tiles/block from double-buffered,
// XOR-swizzled LDS. Unnormalized partials Od[kq], Lp[kq]; merge in ffn_fused.
// ---------------------------------------------------------------------------
__global__ __launch_bounds__(256, 2) void attn_mfma(
        const unsigned short* __restrict__ Qp, const unsigned short* __restrict__ KT,
        const unsigned short* __restrict__ VT2, float* __restrict__ Od,
        float* __restrict__ Lp) {
    __shared__ unsigned short kbuf[2][2048];  // K tile double buffer (4KB ea)
    __shared__ unsigned short vbuf[2][2048];  // V tile double buffer
    __shared__ unsigned int pbuf[4][256];     // per-wave P exchange, pitch 16 dw
    const int tid = threadIdx.x;
    const int lane = tid & 63, w = tid >> 6;  // w = q-subtile
    const int l15 = lane & 15, quad = lane >> 4;
    const int gb = blockIdx.x;                // 0..2047
    const int bh = ((gb & 7) << 1) | ((gb >> 10) & 1);  // XCD-locality swizzle
    const int qc = (gb >> 3) & 31;
    const int kq = (gb >> 8) & 3;                       // key quarter
    const int h  = bh & 3;
    const int b  = bh >> 2;
    const int qrow = qc * 64 + w * 16;
    const int sw = 4 * ((l15 >> 1) & 3);                // pbuf bank swizzle

    short8 aq0, aq1;
    {
        const unsigned short* qptr = Qp + ((size_t)(b * NN + qrow + l15) * DD + h * DHH + 8 * quad);
        aq0 = *(const short8*)qptr;
        aq1 = *(const short8*)(qptr + 32);
    }
    fx4 od0 = (fx4){0.f, 0.f, 0.f, 0.f};
    fx4 od1 = (fx4){0.f, 0.f, 0.f, 0.f};
    fx4 od2 = (fx4){0.f, 0.f, 0.f, 0.f};
    fx4 od3 = (fx4){0.f, 0.f, 0.f, 0.f};
    float lsum = 0.0f;

    unsigned int* pw = &pbuf[w][0];
    const int wcol = (2 * quad) ^ sw;         // write cols (pairs t=2q,2q+1 / +8)
    const int rcol = (4 * quad) ^ sw;         // read col group (t=4Q..4Q+3)
    const unsigned short* ktb = KT  + (size_t)(bh * 64 + kq * 16) * 2048 + tid * 8;
    const unsigned short* vtb = VT2 + (size_t)(bh * 64 + kq * 16) * 2048 + tid * 8;
    // K/V tile swizzle: element e -> e ^ (((e>>6)&3)<<3)  (byte[5:4]^=byte[8:7])
    const int ew = (tid * 8) ^ (((tid >> 3) & 3) << 3);          // stage-write dst
    const int fo = (l15 * 32 + 8 * quad) ^ (((l15 >> 1) & 3) << 3); // frag-read base

    // prologue: stage tile 0 into buffer 0
    {
        uint4v kr = *(const uint4v*)ktb;
        uint4v vr = *(const uint4v*)vtb;
        *(uint4v*)&kbuf[0][ew] = kr;
        *(uint4v*)&vbuf[0][ew] = vr;
    }
    __syncthreads();

    for (int t = 0; t < 16; ++t) {
        const int cur = t & 1;
        const int tn = (t < 15) ? t + 1 : 15;           // clamp (last redundant)
        // issue next-tile global loads FIRST (T14 async split: write after compute)
        uint4v kr = *(const uint4v*)(ktb + (size_t)tn * 2048);
        uint4v vr = *(const uint4v*)(vtb + (size_t)tn * 2048);

        // ---- compute tile t from LDS ----
        const unsigned short* kb = &kbuf[cur][fo];
        short8 ck0 = *(const short8*)(kb);          // keys l15,    d 8q..8q+7
        short8 ck1 = *(const short8*)(kb + 1024);   // keys l15,    d 32+8q..
        short8 ck2 = *(const short8*)(kb + 512);    // keys 16+l15, d 8q..
        short8 ck3 = *(const short8*)(kb + 1536);   // keys 16+l15, d 32+8q..
        const unsigned short* vb = &vbuf[cur][fo];
        short8 cv0 = *(const short8*)(vb);          // d l15,    keys 8q..8q+7
        short8 cv1 = *(const short8*)(vb + 512);    // d 16+l15
        short8 cv2 = *(const short8*)(vb + 1024);   // d 32+l15
        short8 cv3 = *(const short8*)(vb + 1536);   // d 48+l15

        const fx4 z_ = (fx4){0.f, 0.f, 0.f, 0.f};
        fx4 s0 = __builtin_amdgcn_mfma_f32_16x16x32_bf16(ck0, aq0, z_, 0, 0, 0);
        s0     = __builtin_amdgcn_mfma_f32_16x16x32_bf16(ck1, aq1, s0, 0, 0, 0);
        fx4 s1 = __builtin_amdgcn_mfma_f32_16x16x32_bf16(ck2, aq0, z_, 0, 0, 0);
        s1     = __builtin_amdgcn_mfma_f32_16x16x32_bf16(ck3, aq1, s1, 0, 0, 0);
        s0[0] = __expf(s0[0] * 0.125f); s0[1] = __expf(s0[1] * 0.125f);
        s0[2] = __expf(s0[2] * 0.125f); s0[3] = __expf(s0[3] * 0.125f);
        s1[0] = __expf(s1[0] * 0.125f); s1[1] = __expf(s1[1] * 0.125f);
        s1[2] = __expf(s1[2] * 0.125f); s1[3] = __expf(s1[3] * 0.125f);
        lsum += s0[0] + s0[1] + s0[2] + s0[3];
        lsum += s1[0] + s1[1] + s1[2] + s1[3];
        uint2v w1_ = (uint2v){packbf(s0[0], s0[1]), packbf(s0[2], s0[3])};
        uint2v w2_ = (uint2v){packbf(s1[0], s1[1]), packbf(s1[2], s1[3])};
        *(uint2v*)(pw + l15 * 16 + wcol)       = w1_;   // pairs t=2q,2q+1
        *(uint2v*)(pw + l15 * 16 + (wcol ^ 8)) = w2_;   // pairs t=8+2q,8+2q+1
        short8 bp = *(const short8*)(pw + l15 * 16 + rcol);  // keys 8*quad..+7
        od0 = __builtin_amdgcn_mfma_f32_16x16x32_bf16(cv0, bp, od0, 0, 0, 0);
        od1 = __builtin_amdgcn_mfma_f32_16x16x32_bf16(cv1, bp, od1, 0, 0, 0);
        od2 = __builtin_amdgcn_mfma_f32_16x16x32_bf16(cv2, bp, od2, 0, 0, 0);
        od3 = __builtin_amdgcn_mfma_f32_16x16x32_bf16(cv3, bp, od3, 0, 0, 0);

        // ---- land next tile into the other buffer, then sync ----
        *(uint4v*)&kbuf[cur ^ 1][ew] = kr;
        *(uint4v*)&vbuf[cur ^ 1][ew] = vr;
        __syncthreads();
    }

    // per-q partial l (sum over quads); write UNNORMALIZED partials
    lsum += __shfl_xor(lsum, 16);
    lsum += __shfl_xor(lsum, 32);
    const size_t grow = (size_t)(b * NN) + qrow + l15;
    float* obase = Od + (size_t)kq * 2097152 + grow * DD + h * DHH;
    *(fx4*)(obase + 0 * 16 + 4 * quad) = od0;
    *(fx4*)(obase + 1 * 16 + 4 * quad) = od1;
    *(fx4*)(obase + 2 * 16 + 4 * quad) = od2;
    *(fx4*)(obase + 3 * 16 + 4 * quad) = od3;
    if (quad == 0) Lp[(size_t)kq * 32768 + grow * 4 + h] = lsum;
}

// ---------------------------------------------------------------------------
// Fused FFN: merge(Od)/l + Qp residual + LN0 -> O (fp32 global, phase-3
// residual) + As (bf16); ffn1 MFMA -> relu -> Hs (LDS only); ffn2 MFMA ->
// +b2 + O -> LN1 -> out. Block = 32 rows, 512 thr, 8 waves (32 cols each).
// ---------------------------------------------------------------------------
__global__ __launch_bounds__(512) void ffn_fused(
        const float* __restrict__ Od, const float* __restrict__ Lp,
        const unsigned short* __restrict__ Qp,
        const float* __restrict__ g0, const float* __restrict__ be0,
        const unsigned short* __restrict__ WT1, const float* __restrict__ b1,
        const unsigned short* __restrict__ WT2, const float* __restrict__ b2,
        const float* __restrict__ g1, const float* __restrict__ be1,
        float* __restrict__ O, float* __restrict__ out) {
    __shared__ unsigned short As[32 * 264];   // LN0(O) bf16 (ffn1 A)
    __shared__ unsigned short Hs[32 * 264];   // H1 bf16 (ffn2 A)
    __shared__ float lnb[2][8][32];
    const int tid = threadIdx.x;
    const int lane = tid & 63, w = tid >> 6;          // w in 0..7
    const int l15 = lane & 15, quad = lane >> 4;
    const int r0 = blockIdx.x * 32;
    const int c0w = w * 32;
    {   // ---- phase 1: merge + residual + LN0; row = tid>>4, 16 elems ----
        const int row = tid >> 4, c0 = (tid & 15) * 16;
        const size_t grow = r0 + row;
        const int hh = c0 >> 6;
        const float inv = 1.0f / (Lp[grow * 4 + hh] + Lp[32768 + grow * 4 + hh]
                                + Lp[65536 + grow * 4 + hh] + Lp[98304 + grow * 4 + hh]);
        float v[16];
        float s1 = 0.f, s2 = 0.f;
        const float* odp = Od + grow * DD + c0;
#pragma unroll
        for (int j = 0; j < 4; ++j) {
            fx4 m0 = *(const fx4*)(odp + j * 4);
            fx4 m1 = *(const fx4*)(odp + 2097152 + j * 4);
            fx4 m2 = *(const fx4*)(odp + 4194304 + j * 4);
            fx4 m3 = *(const fx4*)(odp + 6291456 + j * 4);
            shortx4 qv = *(const shortx4*)(Qp + grow * DD + c0 + j * 4);
#pragma unroll
            for (int i = 0; i < 4; ++i) {
                float x = (m0[i] + m1[i] + m2[i] + m3[i]) * inv
                        + bf2f((unsigned short)qv[i]);
                v[j * 4 + i] = x; s1 += x; s2 += x * x;
            }
        }
        s1 += __shfl_xor(s1, 1); s2 += __shfl_xor(s2, 1);
        s1 += __shfl_xor(s1, 2); s2 += __shfl_xor(s2, 2);
        s1 += __shfl_xor(s1, 4); s2 += __shfl_xor(s2, 4);
        s1 += __shfl_xor(s1, 8); s2 += __shfl_xor(s2, 8);
        const float mean = s1 * (1.0f / 256.0f);
        const float var  = s2 * (1.0f / 256.0f) - mean * mean;
        const float rstd = rsqrtf(var + 1e-5f);
#pragma unroll
        for (int j = 0; j < 4; ++j) {
            fx4 gg = *(const fx4*)(g0 + c0 + j * 4);
            fx4 ee = *(const fx4*)(be0 + c0 + j * 4);
            fx4 o; shortx4 ob;
#pragma unroll
            for (int i = 0; i < 4; ++i) {
                o[i] = (v[j * 4 + i] - mean) * rstd * gg[i] + ee[i];
                ob[i] = (short)f2bf(o[i]);
            }
            *(fx4*)(O + grow * DD + c0 + j * 4) = o;
            *(shortx4*)(As + row * 264 + c0 + j * 4) = ob;
        }
    }
    // W1 frags + b1
    short8 wf[8][2];
#pragma unroll
    for (int kc = 0; kc < 8; ++kc)
#pragma unroll
        for (int dt = 0; dt < 2; ++dt)
            wf[kc][dt] = *(const short8*)(WT1 + (size_t)(c0w + dt * 16 + l15) * DD + kc * 32 + 8 * quad);
    fx4 bb1[2];
#pragma unroll
    for (int dt = 0; dt < 2; ++dt)
        bb1[dt] = *(const fx4*)(b1 + c0w + dt * 16 + 4 * quad);
    __syncthreads();
    // ---- phase 2: ffn1 MFMA -> relu -> Hs ----
    fx4 acc[2][2];
#pragma unroll
    for (int mt = 0; mt < 2; ++mt)
#pragma unroll
        for (int dt = 0; dt < 2; ++dt) acc[mt][dt] = (fx4){0.f, 0.f, 0.f, 0.f};
#pragma unroll
    for (int kc = 0; kc < 8; ++kc) {
        short8 a0 = *(const short8*)(As + l15 * 264 + kc * 32 + 8 * quad);
        short8 a1 = *(const short8*)(As + (16 + l15) * 264 + kc * 32 + 8 * quad);
#pragma unroll
        for (int dt = 0; dt < 2; ++dt) {
            acc[0][dt] = __builtin_amdgcn_mfma_f32_16x16x32_bf16(wf[kc][dt], a0, acc[0][dt], 0, 0, 0);
            acc[1][dt] = __builtin_amdgcn_mfma_f32_16x16x32_bf16(wf[kc][dt], a1, acc[1][dt], 0, 0, 0);
        }
    }
#pragma unroll
    for (int mt = 0; mt < 2; ++mt) {
#pragma unroll
        for (int dt = 0; dt < 2; ++dt) {
            shortx4 pk;
#pragma unroll
            for (int r = 0; r < 4; ++r)
                pk[r] = (short)f2bf(fmaxf(acc[mt][dt][r] + bb1[dt][r], 0.0f));
            *(shortx4*)(Hs + (mt * 16 + l15) * 264 + c0w + dt * 16 + 4 * quad) = pk;
        }
    }
    // W2 frags + b2 + g1/be1
    short8 wf2[8][2];
#pragma unroll
    for (int kc = 0; kc < 8; ++kc)
#pragma unroll
        for (int dt = 0; dt < 2; ++dt)
            wf2[kc][dt] = *(const short8*)(WT2 + (size_t)(c0w + dt * 16 + l15) * DD + kc * 32 + 8 * quad);
    fx4 bb2[2], gg1[2], ee1[2];
#pragma unroll
    for (int dt = 0; dt < 2; ++dt) {
        int col = c0w + dt * 16 + 4 * quad;
        bb2[dt] = *(const fx4*)(b2 + col);
        gg1[dt] = *(const fx4*)(g1 + col);
        ee1[dt] = *(const fx4*)(be1 + col);
    }
    __syncthreads();
    // ---- phase 3: ffn2 MFMA -> +b2 + O residual -> LN1 -> out ----
    fx4 acc2[2][2];
#pragma unroll
    for (int mt = 0; mt < 2; ++mt)
#pragma unroll
        for (int dt = 0; dt < 2; ++dt) acc2[mt][dt] = (fx4){0.f, 0.f, 0.f, 0.f};
#pragma unroll
    for (int kc = 0; kc < 8; ++kc) {
        short8 a0 = *(const short8*)(Hs + l15 * 264 + kc * 32 + 8 * quad);
        short8 a1 = *(const short8*)(Hs + (16 + l15) * 264 + kc * 32 + 8 * quad);
#pragma unroll
        for (int dt = 0; dt < 2; ++dt) {
            acc2[0][dt] = __builtin_amdgcn_mfma_f32_16x16x32_bf16(wf2[kc][dt], a0, acc2[0][dt], 0, 0, 0);
            acc2[1][dt] = __builtin_amdgcn_mfma_f32_16x16x32_bf16(wf2[kc][dt], a1, acc2[1][dt], 0, 0, 0);
        }
    }
    fx4 v4[2][2];
#pragma unroll
    for (int mt = 0; mt < 2; ++mt) {
        const size_t grow = r0 + mt * 16 + l15;
        float p1 = 0.f, p2 = 0.f;
#pragma unroll
        for (int dt = 0; dt < 2; ++dt) {
            fx4 rv = *(const fx4*)(O + grow * DD + c0w + dt * 16 + 4 * quad);
#pragma unroll
            for (int r = 0; r < 4; ++r) {
                float x = acc2[mt][dt][r] + bb2[dt][r] + rv[r];
                v4[mt][dt][r] = x; p1 += x; p2 += x * x;
            }
        }
        p1 += __shfl_xor(p1, 16); p2 += __shfl_xor(p2, 16);
        p1 += __shfl_xor(p1, 32); p2 += __shfl_xor(p2, 32);
        if (quad == 0) { lnb[0][w][mt * 16 + l15] = p1; lnb[1][w][mt * 16 + l15] = p2; }
    }
    __syncthreads();
#pragma unroll
    for (int mt = 0; mt < 2; ++mt) {
        const int row = mt * 16 + l15;
        float s1 = 0.f, s2 = 0.f;
#pragma unroll
        for (int ww = 0; ww < 8; ++ww) { s1 += lnb[0][ww][row]; s2 += lnb[1][ww][row]; }
        const float mean = s1 * (1.0f / 256.0f);
        const float var  = s2 * (1.0f / 256.0f) - mean * mean;
        const float rstd = rsqrtf(var + 1e-5f);
        const size_t grow = r0 + row;
#pragma unroll
        for (int dt = 0; dt < 2; ++dt) {
            fx4 o;
#pragma unroll
            for (int r = 0; r < 4; ++r)
                o[r] = (v4[mt][dt][r] - mean) * rstd * gg1[dt][r] + ee1[dt][r];
            *(fx4*)(out + grow * DD + c0w + dt * 16 + 4 * quad) = o;
        }
    }
}

extern "C" void kernel_launch(void* const* d_in, const int* in_sizes, int n_in,
                              void* d_out, int out_size, void* d_ws, size_t ws_size,
                              hipStream_t stream) {
    (void)in_sizes; (void)n_in; (void)out_size; (void)ws_size;
    const float* Q     = (const float*)d_in[0];
    const float* K     = (const float*)d_in[1];
    const float* Wq    = (const float*)d_in[2];
    const float* bq    = (const float*)d_in[3];
    const float* Wk    = (const float*)d_in[4];
    const float* bk    = (const float*)d_in[5];
    const float* Wv    = (const float*)d_in[6];
    const float* bv    = (const float*)d_in[7];
    const float* W1    = (const float*)d_in[8];
    const float* b1    = (const float*)d_in[9];
    const float* W2    = (const float*)d_in[10];
    const float* b2    = (const float*)d_in[11];
    const float* g0    = (const float*)d_in[12];
    const float* beta0 = (const float*)d_in[13];
    const float* g1    = (const float*)d_in[14];
    const float* beta1 = (const float*)d_in[15];

    // Workspace: [0,4)Mi Qp bf16; [4,8)Mi KT; [8,12)Mi VT2; [12,44)Mi Od[4];
    // [44,52)Mi O f32; [52,+512K) Lp; [53Mi,+640K) WT x5
    char* ws = (char*)d_ws;
    unsigned short* Qp  = (unsigned short*)(ws);
    unsigned short* KT  = (unsigned short*)(ws + (4u  << 20));
    unsigned short* VT2 = (unsigned short*)(ws + (8u  << 20));
    float*          Od  = (float*)(ws + (12u << 20));   // 4 x 8MB partials
    float*          O   = (float*)(ws + (44u << 20));
    float*          Lp  = (float*)(ws + (52u << 20));
    unsigned short* WT5 = (unsigned short*)(ws + (53u << 20));
    float*          out = (float*)d_out;

    const unsigned short* WT1 = WT5 + 3 * 65536;
    const unsigned short* WT2 = WT5 + 4 * 65536;

    const int M = BB * NN;                        // 8192 rows

    wt_prep<<<dim3(4, 4, 5), 256, 0, stream>>>(Wq, Wk, Wv, W1, W2, WT5);
    qkv_mfma<<<dim3(M / 16, 3), 256, 0, stream>>>(Q, K, WT5, bq, bk, bv, Qp, KT, VT2);
    attn_mfma<<<2048, 256, 0, stream>>>(Qp, KT, VT2, Od, Lp);
    ffn_fused<<<M / 32, 512, 0, stream>>>(Od, Lp, Qp, g0, beta0, WT1, b1,
                                          WT2, b2, g1, beta1, O, out);
}

// Round 13
// 164.151 us; speedup vs baseline: 1.0968x; 1.0041x over previous
//
#include <hip/hip_runtime.h>

// MAB block, MFMA bf16, round 19: fuse K/V projection z-slices.
// r18 post-mortem: ffn fusion -5.9us; fusion/launch-count is the only lever
// that has moved anything since r15 (r17 -9.3, r18 -5.9). Next application:
// qkv z=1 and z=2 both read + stage the same K (8MB fp32 + 32 f2bf/thread,
// duplicated). r19 fuses them: one staged K tile feeds the KT pass
// (transposed acc, mfma(wf,a)) then the VT2 pass (original order,
// mfma(a,wf)). K read 16->8MB, one staging pass gone, grid y 3->2.
// attn/ffn_fused/wt_prep unchanged from r18.

typedef float fx4 __attribute__((ext_vector_type(4)));
typedef short short8 __attribute__((ext_vector_type(8)));
typedef short shortx4 __attribute__((ext_vector_type(4)));
typedef unsigned int uint2v __attribute__((ext_vector_type(2)));
typedef unsigned int uint4v __attribute__((ext_vector_type(4)));

#define BB  4
#define NN  2048
#define DD  256
#define HH  4
#define DHH 64

__device__ __forceinline__ float bf2f(unsigned short u) {
    union { unsigned int i; float f; } v; v.i = ((unsigned int)u) << 16; return v.f;
}
__device__ __forceinline__ unsigned short f2bf(float f) {
    union { float f; unsigned int i; } v; v.f = f;
    unsigned int r = v.i + 0x7FFF + ((v.i >> 16) & 1);   // RNE
    return (unsigned short)(r >> 16);
}
__device__ __forceinline__ unsigned int fbits(float f) {
    union { float f; unsigned int i; } v; v.f = f; return v.i;
}
__device__ __forceinline__ unsigned int packbf(float lo, float hi) {
    unsigned int a = fbits(lo), b = fbits(hi);
    a = (a + 0x7FFF + ((a >> 16) & 1)) >> 16;
    b = (b + 0x7FFF + ((b >> 16) & 1)) & 0xFFFF0000u;
    return a | b;
}

// ---------------------------------------------------------------------------
// Weight prep: WT[n][k] = bf16(W[k][n]) for the 5 weight matrices (256x256).
// ---------------------------------------------------------------------------
__global__ __launch_bounds__(256) void wt_prep(
        const float* __restrict__ w0, const float* __restrict__ w1,
        const float* __restrict__ w2, const float* __restrict__ w3,
        const float* __restrict__ w4, unsigned short* __restrict__ dst) {
    __shared__ unsigned short T[64 * 73];
    const int tid = threadIdx.x;
    const int z = blockIdx.z;
    const float* W = (z == 0) ? w0 : (z == 1) ? w1 : (z == 2) ? w2 : (z == 3) ? w3 : w4;
    unsigned short* WT = dst + z * 65536;
    const int nb = blockIdx.x * 64, kb = blockIdx.y * 64;
    {
        int kl = tid >> 2, c0 = (tid & 3) * 16;
        const float* src = W + (size_t)(kb + kl) * DD + nb + c0;
#pragma unroll
        for (int i = 0; i < 16; ++i) T[kl * 73 + c0 + i] = f2bf(src[i]);
    }
    __syncthreads();
    {
        int nl = tid >> 2, k0 = (tid & 3) * 16;
        short8 o0, o1;
#pragma unroll
        for (int i = 0; i < 8; ++i) {
            o0[i] = (short)T[(k0 + i) * 73 + nl];
            o1[i] = (short)T[(k0 + 8 + i) * 73 + nl];
        }
        short8* d = (short8*)(WT + (size_t)(nb + nl) * DD + kb + k0);
        d[0] = o0; d[1] = o1;
    }
}

// ---------------------------------------------------------------------------
// Shared A-staging: 32x256 fp32 -> bf16 into As (pitch 264).
// ---------------------------------------------------------------------------
__device__ __forceinline__ void stage_a32(
        const float* __restrict__ Ain, unsigned short* __restrict__ As,
        int r0, int tid) {
    int row = tid >> 3, c0 = (tid & 7) * 32;
    short8 o[4];
    const fx4* s4 = (const fx4*)(Ain + (size_t)(r0 + row) * DD + c0);
#pragma unroll
    for (int j = 0; j < 4; ++j) {
        fx4 v0 = s4[2 * j], v1 = s4[2 * j + 1];
#pragma unroll
        for (int i = 0; i < 4; ++i) {
            o[j][i]     = (short)f2bf(v0[i]);
            o[j][i + 4] = (short)f2bf(v1[i]);
        }
    }
    short8* d = (short8*)(As + row * 264 + c0);
#pragma unroll
    for (int j = 0; j < 4; ++j) d[j] = o[j];
}

// ---------------------------------------------------------------------------
// Q projection: row-major Qp (transposed acc, mfma(wf,a)). 32-row tile.
// ---------------------------------------------------------------------------
__device__ __forceinline__ void q_body(
        const float* __restrict__ Ain, const unsigned short* __restrict__ WT,
        const float* __restrict__ bias, unsigned short* __restrict__ Cout, int bx) {
    __shared__ unsigned short As[32 * 264];
    const int tid = threadIdx.x;
    const int lane = tid & 63, w = tid >> 6;
    const int l15 = lane & 15, quad = lane >> 4;
    const int r0 = (bx >> 1) * 32;
    const int c0w = (bx & 1) * 128 + w * 32;
    short8 wf[8][2];
#pragma unroll
    for (int kc = 0; kc < 8; ++kc)
#pragma unroll
        for (int dt = 0; dt < 2; ++dt)
            wf[kc][dt] = *(const short8*)(WT + (size_t)(c0w + dt * 16 + l15) * DD + kc * 32 + 8 * quad);
    fx4 bb[2];
#pragma unroll
    for (int dt = 0; dt < 2; ++dt)
        bb[dt] = *(const fx4*)(bias + c0w + dt * 16 + 4 * quad);
    stage_a32(Ain, As, r0, tid);
    __syncthreads();
    fx4 acc[2][2];
#pragma unroll
    for (int mt = 0; mt < 2; ++mt)
#pragma unroll
        for (int dt = 0; dt < 2; ++dt) acc[mt][dt] = (fx4){0.f, 0.f, 0.f, 0.f};
#pragma unroll
    for (int kc = 0; kc < 8; ++kc) {
        short8 a0 = *(const short8*)(As + l15 * 264 + kc * 32 + 8 * quad);
        short8 a1 = *(const short8*)(As + (16 + l15) * 264 + kc * 32 + 8 * quad);
#pragma unroll
        for (int dt = 0; dt < 2; ++dt) {
            acc[0][dt] = __builtin_amdgcn_mfma_f32_16x16x32_bf16(wf[kc][dt], a0, acc[0][dt], 0, 0, 0);
            acc[1][dt] = __builtin_amdgcn_mfma_f32_16x16x32_bf16(wf[kc][dt], a1, acc[1][dt], 0, 0, 0);
        }
    }
#pragma unroll
    for (int mt = 0; mt < 2; ++mt) {
        const size_t grow = r0 + mt * 16 + l15;
#pragma unroll
        for (int dt = 0; dt < 2; ++dt) {
            shortx4 pk;
#pragma unroll
            for (int r = 0; r < 4; ++r) pk[r] = (short)f2bf(acc[mt][dt][r] + bb[dt][r]);
            *(shortx4*)(Cout + grow * DD + c0w + dt * 16 + 4 * quad) = pk;
        }
    }
}

// ---------------------------------------------------------------------------
// Fused K+V projection: stage K once; pass 1 -> KT (transposed acc),
// pass 2 -> VT2 (original order). Register lifetimes disjoint.
// ---------------------------------------------------------------------------
__device__ __forceinline__ void kv_body(
        const float* __restrict__ Kin, const unsigned short* __restrict__ WTk,
        const unsigned short* __restrict__ WTv,
        const float* __restrict__ bk, const float* __restrict__ bvv,
        unsigned short* __restrict__ KT, unsigned short* __restrict__ VT2, int bx) {
    __shared__ unsigned short As[32 * 264];
    const int tid = threadIdx.x;
    const int lane = tid & 63, w = tid >> 6;
    const int l15 = lane & 15, quad = lane >> 4;
    const int r0 = (bx >> 1) * 32;
    const int c0w = (bx & 1) * 128 + w * 32;
    const int tl = (r0 & 2047) >> 5;
    const int b  = r0 >> 11;
    stage_a32(Kin, As, r0, tid);
    __syncthreads();
    {   // ---- pass 1: K -> KT (transposed acc, mfma(wf, a)) ----
        short8 wf[8][2];
#pragma unroll
        for (int kc = 0; kc < 8; ++kc)
#pragma unroll
            for (int dt = 0; dt < 2; ++dt)
                wf[kc][dt] = *(const short8*)(WTk + (size_t)(c0w + dt * 16 + l15) * DD + kc * 32 + 8 * quad);
        fx4 bb[2];
#pragma unroll
        for (int dt = 0; dt < 2; ++dt)
            bb[dt] = *(const fx4*)(bk + c0w + dt * 16 + 4 * quad);
        fx4 acc[2][2];
#pragma unroll
        for (int mt = 0; mt < 2; ++mt)
#pragma unroll
            for (int dt = 0; dt < 2; ++dt) acc[mt][dt] = (fx4){0.f, 0.f, 0.f, 0.f};
#pragma unroll
        for (int kc = 0; kc < 8; ++kc) {
            short8 a0 = *(const short8*)(As + l15 * 264 + kc * 32 + 8 * quad);
            short8 a1 = *(const short8*)(As + (16 + l15) * 264 + kc * 32 + 8 * quad);
#pragma unroll
            for (int dt = 0; dt < 2; ++dt) {
                acc[0][dt] = __builtin_amdgcn_mfma_f32_16x16x32_bf16(wf[kc][dt], a0, acc[0][dt], 0, 0, 0);
                acc[1][dt] = __builtin_amdgcn_mfma_f32_16x16x32_bf16(wf[kc][dt], a1, acc[1][dt], 0, 0, 0);
            }
        }
        // KT: col = c0w+dt*16+4*quad+r (d), key = mt*16+l15
#pragma unroll
        for (int mt = 0; mt < 2; ++mt) {
            const int key32 = mt * 16 + l15;
#pragma unroll
            for (int dt = 0; dt < 2; ++dt) {
                const int col = c0w + dt * 16 + 4 * quad;
                shortx4 pk;
#pragma unroll
                for (int r = 0; r < 4; ++r) pk[r] = (short)f2bf(acc[mt][dt][r] + bb[dt][r]);
                unsigned short* dstp = KT
                    + ((size_t)((b * 4 + (col >> 6)) * 64 + tl)) * 2048
                    + ((col >> 5) & 1) * 1024 + key32 * 32 + (col & 31);
                *(shortx4*)dstp = pk;
            }
        }
    }
    {   // ---- pass 2: K -> VT2 (original order, mfma(a, wf)) ----
        short8 wf[8][2];
#pragma unroll
        for (int kc = 0; kc < 8; ++kc)
#pragma unroll
            for (int dt = 0; dt < 2; ++dt)
                wf[kc][dt] = *(const short8*)(WTv + (size_t)(c0w + dt * 16 + l15) * DD + kc * 32 + 8 * quad);
        float bv[2];
#pragma unroll
        for (int dt = 0; dt < 2; ++dt) bv[dt] = bvv[c0w + dt * 16 + l15];
        fx4 acc[2][2];
#pragma unroll
        for (int mt = 0; mt < 2; ++mt)
#pragma unroll
            for (int dt = 0; dt < 2; ++dt) acc[mt][dt] = (fx4){0.f, 0.f, 0.f, 0.f};
#pragma unroll
        for (int kc = 0; kc < 8; ++kc) {
            short8 a0 = *(const short8*)(As + l15 * 264 + kc * 32 + 8 * quad);
            short8 a1 = *(const short8*)(As + (16 + l15) * 264 + kc * 32 + 8 * quad);
#pragma unroll
            for (int dt = 0; dt < 2; ++dt) {
                acc[0][dt] = __builtin_amdgcn_mfma_f32_16x16x32_bf16(a0, wf[kc][dt], acc[0][dt], 0, 0, 0);
                acc[1][dt] = __builtin_amdgcn_mfma_f32_16x16x32_bf16(a1, wf[kc][dt], acc[1][dt], 0, 0, 0);
            }
        }
        // VT2: key = r0+mt*16+4*quad+r, col = c0w+dt*16+l15 (d)
#pragma unroll
        for (int mt = 0; mt < 2; ++mt) {
#pragma unroll
            for (int dt = 0; dt < 2; ++dt) {
                const int col = c0w + dt * 16 + l15;
                shortx4 pk;
#pragma unroll
                for (int r = 0; r < 4; ++r) pk[r] = (short)f2bf(acc[mt][dt][r] + bv[dt]);
                unsigned short* dstp = VT2
                    + ((size_t)((b * 4 + (col >> 6)) * 64 + tl)) * 2048
                    + (col & 63) * 32 + mt * 16 + 4 * quad;
                *(shortx4*)dstp = pk;
            }
        }
    }
}

// Fused QKV projections: grid (512, 2); y=0: Q->Qp, y=1: K->{KT,VT2}.
__global__ __launch_bounds__(256, 4) void qkv_mfma(
        const float* __restrict__ Q, const float* __restrict__ K,
        const unsigned short* __restrict__ WT5,
        const float* __restrict__ bq, const float* __restrict__ bk,
        const float* __restrict__ bv,
        unsigned short* __restrict__ Qp, unsigned short* __restrict__ KT,
        unsigned short* __restrict__ VT2) {
    if (blockIdx.y == 0) q_body(Q, WT5, bq, Qp, blockIdx.x);
    else kv_body(K, WT5 + 65536, WT5 + 131072, bk, bv, KT, VT2, blockIdx.x);
}

// ---------------------------------------------------------------------------
// Flash attention, O^T form, no-max softmax. r15 structure (unchanged):
// Block = 64 q-rows x 512 keys (kq quarter), grid 2048 -> 8 blocks/CU.
// 4 waves = 4 q-subtiles; 16 key-tiles/block from double-buffered,
// XOR-swizzled LDS. Unnormalized partials Od[kq], Lp[kq]; merge in ffn_fused.
// ---------------------------------------------------------------------------
__global__ __launch_bounds__(256, 2) void attn_mfma(
        const unsigned short* __restrict__ Qp, const unsigned short* __restrict__ KT,
        const unsigned short* __restrict__ VT2, float* __restrict__ Od,
        float* __restrict__ Lp) {
    __shared__ unsigned short kbuf[2][2048];  // K tile double buffer (4KB ea)
    __shared__ unsigned short vbuf[2][2048];  // V tile double buffer
    __shared__ unsigned int pbuf[4][256];     // per-wave P exchange, pitch 16 dw
    const int tid = threadIdx.x;
    const int lane = tid & 63, w = tid >> 6;  // w = q-subtile
    const int l15 = lane & 15, quad = lane >> 4;
    const int gb = blockIdx.x;                // 0..2047
    const int bh = ((gb & 7) << 1) | ((gb >> 10) & 1);  // XCD-locality swizzle
    const int qc = (gb >> 3) & 31;
    const int kq = (gb >> 8) & 3;                       // key quarter
    const int h  = bh & 3;
    const int b  = bh >> 2;
    const int qrow = qc * 64 + w * 16;
    const int sw = 4 * ((l15 >> 1) & 3);                // pbuf bank swizzle

    short8 aq0, aq1;
    {
        const unsigned short* qptr = Qp + ((size_t)(b * NN + qrow + l15) * DD + h * DHH + 8 * quad);
        aq0 = *(const short8*)qptr;
        aq1 = *(const short8*)(qptr + 32);
    }
    fx4 od0 = (fx4){0.f, 0.f, 0.f, 0.f};
    fx4 od1 = (fx4){0.f, 0.f, 0.f, 0.f};
    fx4 od2 = (fx4){0.f, 0.f, 0.f, 0.f};
    fx4 od3 = (fx4){0.f, 0.f, 0.f, 0.f};
    float lsum = 0.0f;

    unsigned int* pw = &pbuf[w][0];
    const int wcol = (2 * quad) ^ sw;         // write cols (pairs t=2q,2q+1 / +8)
    const int rcol = (4 * quad) ^ sw;         // read col group (t=4Q..4Q+3)
    const unsigned short* ktb = KT  + (size_t)(bh * 64 + kq * 16) * 2048 + tid * 8;
    const unsigned short* vtb = VT2 + (size_t)(bh * 64 + kq * 16) * 2048 + tid * 8;
    // K/V tile swizzle: element e -> e ^ (((e>>6)&3)<<3)  (byte[5:4]^=byte[8:7])
    const int ew = (tid * 8) ^ (((tid >> 3) & 3) << 3);          // stage-write dst
    const int fo = (l15 * 32 + 8 * quad) ^ (((l15 >> 1) & 3) << 3); // frag-read base

    // prologue: stage tile 0 into buffer 0
    {
        uint4v kr = *(const uint4v*)ktb;
        uint4v vr = *(const uint4v*)vtb;
        *(uint4v*)&kbuf[0][ew] = kr;
        *(uint4v*)&vbuf[0][ew] = vr;
    }
    __syncthreads();

    for (int t = 0; t < 16; ++t) {
        const int cur = t & 1;
        const int tn = (t < 15) ? t + 1 : 15;           // clamp (last redundant)
        // issue next-tile global loads FIRST (T14 async split: write after compute)
        uint4v kr = *(const uint4v*)(ktb + (size_t)tn * 2048);
        uint4v vr = *(const uint4v*)(vtb + (size_t)tn * 2048);

        // ---- compute tile t from LDS ----
        const unsigned short* kb = &kbuf[cur][fo];
        short8 ck0 = *(const short8*)(kb);          // keys l15,    d 8q..8q+7
        short8 ck1 = *(const short8*)(kb + 1024);   // keys l15,    d 32+8q..
        short8 ck2 = *(const short8*)(kb + 512);    // keys 16+l15, d 8q..
        short8 ck3 = *(const short8*)(kb + 1536);   // keys 16+l15, d 32+8q..
        const unsigned short* vb = &vbuf[cur][fo];
        short8 cv0 = *(const short8*)(vb);          // d l15,    keys 8q..8q+7
        short8 cv1 = *(const short8*)(vb + 512);    // d 16+l15
        short8 cv2 = *(const short8*)(vb + 1024);   // d 32+l15
        short8 cv3 = *(const short8*)(vb + 1536);   // d 48+l15

        const fx4 z_ = (fx4){0.f, 0.f, 0.f, 0.f};
        fx4 s0 = __builtin_amdgcn_mfma_f32_16x16x32_bf16(ck0, aq0, z_, 0, 0, 0);
        s0     = __builtin_amdgcn_mfma_f32_16x16x32_bf16(ck1, aq1, s0, 0, 0, 0);
        fx4 s1 = __builtin_amdgcn_mfma_f32_16x16x32_bf16(ck2, aq0, z_, 0, 0, 0);
        s1     = __builtin_amdgcn_mfma_f32_16x16x32_bf16(ck3, aq1, s1, 0, 0, 0);
        s0[0] = __expf(s0[0] * 0.125f); s0[1] = __expf(s0[1] * 0.125f);
        s0[2] = __expf(s0[2] * 0.125f); s0[3] = __expf(s0[3] * 0.125f);
        s1[0] = __expf(s1[0] * 0.125f); s1[1] = __expf(s1[1] * 0.125f);
        s1[2] = __expf(s1[2] * 0.125f); s1[3] = __expf(s1[3] * 0.125f);
        lsum += s0[0] + s0[1] + s0[2] + s0[3];
        lsum += s1[0] + s1[1] + s1[2] + s1[3];
        uint2v w1_ = (uint2v){packbf(s0[0], s0[1]), packbf(s0[2], s0[3])};
        uint2v w2_ = (uint2v){packbf(s1[0], s1[1]), packbf(s1[2], s1[3])};
        *(uint2v*)(pw + l15 * 16 + wcol)       = w1_;   // pairs t=2q,2q+1
        *(uint2v*)(pw + l15 * 16 + (wcol ^ 8)) = w2_;   // pairs t=8+2q,8+2q+1
        short8 bp = *(const short8*)(pw + l15 * 16 + rcol);  // keys 8*quad..+7
        od0 = __builtin_amdgcn_mfma_f32_16x16x32_bf16(cv0, bp, od0, 0, 0, 0);
        od1 = __builtin_amdgcn_mfma_f32_16x16x32_bf16(cv1, bp, od1, 0, 0, 0);
        od2 = __builtin_amdgcn_mfma_f32_16x16x32_bf16(cv2, bp, od2, 0, 0, 0);
        od3 = __builtin_amdgcn_mfma_f32_16x16x32_bf16(cv3, bp, od3, 0, 0, 0);

        // ---- land next tile into the other buffer, then sync ----
        *(uint4v*)&kbuf[cur ^ 1][ew] = kr;
        *(uint4v*)&vbuf[cur ^ 1][ew] = vr;
        __syncthreads();
    }

    // per-q partial l (sum over quads); write UNNORMALIZED partials
    lsum += __shfl_xor(lsum, 16);
    lsum += __shfl_xor(lsum, 32);
    const size_t grow = (size_t)(b * NN) + qrow + l15;
    float* obase = Od + (size_t)kq * 2097152 + grow * DD + h * DHH;
    *(fx4*)(obase + 0 * 16 + 4 * quad) = od0;
    *(fx4*)(obase + 1 * 16 + 4 * quad) = od1;
    *(fx4*)(obase + 2 * 16 + 4 * quad) = od2;
    *(fx4*)(obase + 3 * 16 + 4 * quad) = od3;
    if (quad == 0) Lp[(size_t)kq * 32768 + grow * 4 + h] = lsum;
}

// ---------------------------------------------------------------------------
// Fused FFN: merge(Od)/l + Qp residual + LN0 -> O (fp32 global, phase-3
// residual) + As (bf16); ffn1 MFMA -> relu -> Hs (LDS only); ffn2 MFMA ->
// +b2 + O -> LN1 -> out. Block = 32 rows, 512 thr, 8 waves (32 cols each).
// ---------------------------------------------------------------------------
__global__ __launch_bounds__(512) void ffn_fused(
        const float* __restrict__ Od, const float* __restrict__ Lp,
        const unsigned short* __restrict__ Qp,
        const float* __restrict__ g0, const float* __restrict__ be0,
        const unsigned short* __restrict__ WT1, const float* __restrict__ b1,
        const unsigned short* __restrict__ WT2, const float* __restrict__ b2,
        const float* __restrict__ g1, const float* __restrict__ be1,
        float* __restrict__ O, float* __restrict__ out) {
    __shared__ unsigned short As[32 * 264];   // LN0(O) bf16 (ffn1 A)
    __shared__ unsigned short Hs[32 * 264];   // H1 bf16 (ffn2 A)
    __shared__ float lnb[2][8][32];
    const int tid = threadIdx.x;
    const int lane = tid & 63, w = tid >> 6;          // w in 0..7
    const int l15 = lane & 15, quad = lane >> 4;
    const int r0 = blockIdx.x * 32;
    const int c0w = w * 32;
    {   // ---- phase 1: merge + residual + LN0; row = tid>>4, 16 elems ----
        const int row = tid >> 4, c0 = (tid & 15) * 16;
        const size_t grow = r0 + row;
        const int hh = c0 >> 6;
        const float inv = 1.0f / (Lp[grow * 4 + hh] + Lp[32768 + grow * 4 + hh]
                                + Lp[65536 + grow * 4 + hh] + Lp[98304 + grow * 4 + hh]);
        float v[16];
        float s1 = 0.f, s2 = 0.f;
        const float* odp = Od + grow * DD + c0;
#pragma unroll
        for (int j = 0; j < 4; ++j) {
            fx4 m0 = *(const fx4*)(odp + j * 4);
            fx4 m1 = *(const fx4*)(odp + 2097152 + j * 4);
            fx4 m2 = *(const fx4*)(odp + 4194304 + j * 4);
            fx4 m3 = *(const fx4*)(odp + 6291456 + j * 4);
            shortx4 qv = *(const shortx4*)(Qp + grow * DD + c0 + j * 4);
#pragma unroll
            for (int i = 0; i < 4; ++i) {
                float x = (m0[i] + m1[i] + m2[i] + m3[i]) * inv
                        + bf2f((unsigned short)qv[i]);
                v[j * 4 + i] = x; s1 += x; s2 += x * x;
            }
        }
        s1 += __shfl_xor(s1, 1); s2 += __shfl_xor(s2, 1);
        s1 += __shfl_xor(s1, 2); s2 += __shfl_xor(s2, 2);
        s1 += __shfl_xor(s1, 4); s2 += __shfl_xor(s2, 4);
        s1 += __shfl_xor(s1, 8); s2 += __shfl_xor(s2, 8);
        const float mean = s1 * (1.0f / 256.0f);
        const float var  = s2 * (1.0f / 256.0f) - mean * mean;
        const float rstd = rsqrtf(var + 1e-5f);
#pragma unroll
        for (int j = 0; j < 4; ++j) {
            fx4 gg = *(const fx4*)(g0 + c0 + j * 4);
            fx4 ee = *(const fx4*)(be0 + c0 + j * 4);
            fx4 o; shortx4 ob;
#pragma unroll
            for (int i = 0; i < 4; ++i) {
                o[i] = (v[j * 4 + i] - mean) * rstd * gg[i] + ee[i];
                ob[i] = (short)f2bf(o[i]);
            }
            *(fx4*)(O + grow * DD + c0 + j * 4) = o;
            *(shortx4*)(As + row * 264 + c0 + j * 4) = ob;
        }
    }
    // W1 frags + b1
    short8 wf[8][2];
#pragma unroll
    for (int kc = 0; kc < 8; ++kc)
#pragma unroll
        for (int dt = 0; dt < 2; ++dt)
            wf[kc][dt] = *(const short8*)(WT1 + (size_t)(c0w + dt * 16 + l15) * DD + kc * 32 + 8 * quad);
    fx4 bb1[2];
#pragma unroll
    for (int dt = 0; dt < 2; ++dt)
        bb1[dt] = *(const fx4*)(b1 + c0w + dt * 16 + 4 * quad);
    __syncthreads();
    // ---- phase 2: ffn1 MFMA -> relu -> Hs ----
    fx4 acc[2][2];
#pragma unroll
    for (int mt = 0; mt < 2; ++mt)
#pragma unroll
        for (int dt = 0; dt < 2; ++dt) acc[mt][dt] = (fx4){0.f, 0.f, 0.f, 0.f};
#pragma unroll
    for (int kc = 0; kc < 8; ++kc) {
        short8 a0 = *(const short8*)(As + l15 * 264 + kc * 32 + 8 * quad);
        short8 a1 = *(const short8*)(As + (16 + l15) * 264 + kc * 32 + 8 * quad);
#pragma unroll
        for (int dt = 0; dt < 2; ++dt) {
            acc[0][dt] = __builtin_amdgcn_mfma_f32_16x16x32_bf16(wf[kc][dt], a0, acc[0][dt], 0, 0, 0);
            acc[1][dt] = __builtin_amdgcn_mfma_f32_16x16x32_bf16(wf[kc][dt], a1, acc[1][dt], 0, 0, 0);
        }
    }
#pragma unroll
    for (int mt = 0; mt < 2; ++mt) {
#pragma unroll
        for (int dt = 0; dt < 2; ++dt) {
            shortx4 pk;
#pragma unroll
            for (int r = 0; r < 4; ++r)
                pk[r] = (short)f2bf(fmaxf(acc[mt][dt][r] + bb1[dt][r], 0.0f));
            *(shortx4*)(Hs + (mt * 16 + l15) * 264 + c0w + dt * 16 + 4 * quad) = pk;
        }
    }
    // W2 frags + b2 + g1/be1
    short8 wf2[8][2];
#pragma unroll
    for (int kc = 0; kc < 8; ++kc)
#pragma unroll
        for (int dt = 0; dt < 2; ++dt)
            wf2[kc][dt] = *(const short8*)(WT2 + (size_t)(c0w + dt * 16 + l15) * DD + kc * 32 + 8 * quad);
    fx4 bb2[2], gg1[2], ee1[2];
#pragma unroll
    for (int dt = 0; dt < 2; ++dt) {
        int col = c0w + dt * 16 + 4 * quad;
        bb2[dt] = *(const fx4*)(b2 + col);
        gg1[dt] = *(const fx4*)(g1 + col);
        ee1[dt] = *(const fx4*)(be1 + col);
    }
    __syncthreads();
    // ---- phase 3: ffn2 MFMA -> +b2 + O residual -> LN1 -> out ----
    fx4 acc2[2][2];
#pragma unroll
    for (int mt = 0; mt < 2; ++mt)
#pragma unroll
        for (int dt = 0; dt < 2; ++dt) acc2[mt][dt] = (fx4){0.f, 0.f, 0.f, 0.f};
#pragma unroll
    for (int kc = 0; kc < 8; ++kc) {
        short8 a0 = *(const short8*)(Hs + l15 * 264 + kc * 32 + 8 * quad);
        short8 a1 = *(const short8*)(Hs + (16 + l15) * 264 + kc * 32 + 8 * quad);
#pragma unroll
        for (int dt = 0; dt < 2; ++dt) {
            acc2[0][dt] = __builtin_amdgcn_mfma_f32_16x16x32_bf16(wf2[kc][dt], a0, acc2[0][dt], 0, 0, 0);
            acc2[1][dt] = __builtin_amdgcn_mfma_f32_16x16x32_bf16(wf2[kc][dt], a1, acc2[1][dt], 0, 0, 0);
        }
    }
    fx4 v4[2][2];
#pragma unroll
    for (int mt = 0; mt < 2; ++mt) {
        const size_t grow = r0 + mt * 16 + l15;
        float p1 = 0.f, p2 = 0.f;
#pragma unroll
        for (int dt = 0; dt < 2; ++dt) {
            fx4 rv = *(const fx4*)(O + grow * DD + c0w + dt * 16 + 4 * quad);
#pragma unroll
            for (int r = 0; r < 4; ++r) {
                float x = acc2[mt][dt][r] + bb2[dt][r] + rv[r];
                v4[mt][dt][r] = x; p1 += x; p2 += x * x;
            }
        }
        p1 += __shfl_xor(p1, 16); p2 += __shfl_xor(p2, 16);
        p1 += __shfl_xor(p1, 32); p2 += __shfl_xor(p2, 32);
        if (quad == 0) { lnb[0][w][mt * 16 + l15] = p1; lnb[1][w][mt * 16 + l15] = p2; }
    }
    __syncthreads();
#pragma unroll
    for (int mt = 0; mt < 2; ++mt) {
        const int row = mt * 16 + l15;
        float s1 = 0.f, s2 = 0.f;
#pragma unroll
        for (int ww = 0; ww < 8; ++ww) { s1 += lnb[0][ww][row]; s2 += lnb[1][ww][row]; }
        const float mean = s1 * (1.0f / 256.0f);
        const float var  = s2 * (1.0f / 256.0f) - mean * mean;
        const float rstd = rsqrtf(var + 1e-5f);
        const size_t grow = r0 + row;
#pragma unroll
        for (int dt = 0; dt < 2; ++dt) {
            fx4 o;
#pragma unroll
            for (int r = 0; r < 4; ++r)
                o[r] = (v4[mt][dt][r] - mean) * rstd * gg1[dt][r] + ee1[dt][r];
            *(fx4*)(out + grow * DD + c0w + dt * 16 + 4 * quad) = o;
        }
    }
}

extern "C" void kernel_launch(void* const* d_in, const int* in_sizes, int n_in,
                              void* d_out, int out_size, void* d_ws, size_t ws_size,
                              hipStream_t stream) {
    (void)in_sizes; (void)n_in; (void)out_size; (void)ws_size;
    const float* Q     = (const float*)d_in[0];
    const float* K     = (const float*)d_in[1];
    const float* Wq    = (const float*)d_in[2];
    const float* bq    = (const float*)d_in[3];
    const float* Wk    = (const float*)d_in[4];
    const float* bk    = (const float*)d_in[5];
    const float* Wv    = (const float*)d_in[6];
    const float* bv    = (const float*)d_in[7];
    const float* W1    = (const float*)d_in[8];
    const float* b1    = (const float*)d_in[9];
    const float* W2    = (const float*)d_in[10];
    const float* b2    = (const float*)d_in[11];
    const float* g0    = (const float*)d_in[12];
    const float* beta0 = (const float*)d_in[13];
    const float* g1    = (const float*)d_in[14];
    const float* beta1 = (const float*)d_in[15];

    // Workspace: [0,4)Mi Qp bf16; [4,8)Mi KT; [8,12)Mi VT2; [12,44)Mi Od[4];
    // [44,52)Mi O f32; [52,+512K) Lp; [53Mi,+640K) WT x5
    char* ws = (char*)d_ws;
    unsigned short* Qp  = (unsigned short*)(ws);
    unsigned short* KT  = (unsigned short*)(ws + (4u  << 20));
    unsigned short* VT2 = (unsigned short*)(ws + (8u  << 20));
    float*          Od  = (float*)(ws + (12u << 20));   // 4 x 8MB partials
    float*          O   = (float*)(ws + (44u << 20));
    float*          Lp  = (float*)(ws + (52u << 20));
    unsigned short* WT5 = (unsigned short*)(ws + (53u << 20));
    float*          out = (float*)d_out;

    const unsigned short* WT1 = WT5 + 3 * 65536;
    const unsigned short* WT2 = WT5 + 4 * 65536;

    const int M = BB * NN;                        // 8192 rows

    wt_prep<<<dim3(4, 4, 5), 256, 0, stream>>>(Wq, Wk, Wv, W1, W2, WT5);
    qkv_mfma<<<dim3(M / 16, 2), 256, 0, stream>>>(Q, K, WT5, bq, bk, bv, Qp, KT, VT2);
    attn_mfma<<<2048, 256, 0, stream>>>(Qp, KT, VT2, Od, Lp);
    ffn_fused<<<M / 32, 512, 0, stream>>>(Od, Lp, Qp, g0, beta0, WT1, b1,
                                          WT2, b2, g1, beta1, O, out);
}

// Round 14
// 162.029 us; speedup vs baseline: 1.1111x; 1.0131x over previous
//
#include <hip/hip_runtime.h>

// MAB block, MFMA bf16, round 20: 2 q-subtiles per wave in attention.
// r19 post-mortem: fusion lever saturated (-0.7us). attn (~37us) budget:
// per wave-tile the LDS unit issues 8 frag reads + 2 stage writes + 3 pbuf
// ops ~= 144cy -> 74k cy/CU ~= 31us: attn is LDS-throughput bound, dominated
// by 4x frag re-read amplification (each wave reads the whole 8KB tile for
// only 16 q-rows). r20: wave owns 32 q-rows (aq0..aq3) -> ck/cv read ONCE,
// QK+softmax+PV for both subtiles -> LDS reads/stage/barriers per q-row
// halve. Block = 128 q x 512 keys, grid 1024 (4 blk/CU). MFMA unchanged.

typedef float fx4 __attribute__((ext_vector_type(4)));
typedef short short8 __attribute__((ext_vector_type(8)));
typedef short shortx4 __attribute__((ext_vector_type(4)));
typedef unsigned int uint2v __attribute__((ext_vector_type(2)));
typedef unsigned int uint4v __attribute__((ext_vector_type(4)));

#define BB  4
#define NN  2048
#define DD  256
#define HH  4
#define DHH 64

__device__ __forceinline__ float bf2f(unsigned short u) {
    union { unsigned int i; float f; } v; v.i = ((unsigned int)u) << 16; return v.f;
}
__device__ __forceinline__ unsigned short f2bf(float f) {
    union { float f; unsigned int i; } v; v.f = f;
    unsigned int r = v.i + 0x7FFF + ((v.i >> 16) & 1);   // RNE
    return (unsigned short)(r >> 16);
}
__device__ __forceinline__ unsigned int fbits(float f) {
    union { float f; unsigned int i; } v; v.f = f; return v.i;
}
__device__ __forceinline__ unsigned int packbf(float lo, float hi) {
    unsigned int a = fbits(lo), b = fbits(hi);
    a = (a + 0x7FFF + ((a >> 16) & 1)) >> 16;
    b = (b + 0x7FFF + ((b >> 16) & 1)) & 0xFFFF0000u;
    return a | b;
}

// ---------------------------------------------------------------------------
// Weight prep: WT[n][k] = bf16(W[k][n]) for the 5 weight matrices (256x256).
// ---------------------------------------------------------------------------
__global__ __launch_bounds__(256) void wt_prep(
        const float* __restrict__ w0, const float* __restrict__ w1,
        const float* __restrict__ w2, const float* __restrict__ w3,
        const float* __restrict__ w4, unsigned short* __restrict__ dst) {
    __shared__ unsigned short T[64 * 73];
    const int tid = threadIdx.x;
    const int z = blockIdx.z;
    const float* W = (z == 0) ? w0 : (z == 1) ? w1 : (z == 2) ? w2 : (z == 3) ? w3 : w4;
    unsigned short* WT = dst + z * 65536;
    const int nb = blockIdx.x * 64, kb = blockIdx.y * 64;
    {
        int kl = tid >> 2, c0 = (tid & 3) * 16;
        const float* src = W + (size_t)(kb + kl) * DD + nb + c0;
#pragma unroll
        for (int i = 0; i < 16; ++i) T[kl * 73 + c0 + i] = f2bf(src[i]);
    }
    __syncthreads();
    {
        int nl = tid >> 2, k0 = (tid & 3) * 16;
        short8 o0, o1;
#pragma unroll
        for (int i = 0; i < 8; ++i) {
            o0[i] = (short)T[(k0 + i) * 73 + nl];
            o1[i] = (short)T[(k0 + 8 + i) * 73 + nl];
        }
        short8* d = (short8*)(WT + (size_t)(nb + nl) * DD + kb + k0);
        d[0] = o0; d[1] = o1;
    }
}

// ---------------------------------------------------------------------------
// Shared A-staging: 32x256 fp32 -> bf16 into As (pitch 264).
// ---------------------------------------------------------------------------
__device__ __forceinline__ void stage_a32(
        const float* __restrict__ Ain, unsigned short* __restrict__ As,
        int r0, int tid) {
    int row = tid >> 3, c0 = (tid & 7) * 32;
    short8 o[4];
    const fx4* s4 = (const fx4*)(Ain + (size_t)(r0 + row) * DD + c0);
#pragma unroll
    for (int j = 0; j < 4; ++j) {
        fx4 v0 = s4[2 * j], v1 = s4[2 * j + 1];
#pragma unroll
        for (int i = 0; i < 4; ++i) {
            o[j][i]     = (short)f2bf(v0[i]);
            o[j][i + 4] = (short)f2bf(v1[i]);
        }
    }
    short8* d = (short8*)(As + row * 264 + c0);
#pragma unroll
    for (int j = 0; j < 4; ++j) d[j] = o[j];
}

// ---------------------------------------------------------------------------
// Q projection: row-major Qp (transposed acc, mfma(wf,a)). 32-row tile.
// ---------------------------------------------------------------------------
__device__ __forceinline__ void q_body(
        const float* __restrict__ Ain, const unsigned short* __restrict__ WT,
        const float* __restrict__ bias, unsigned short* __restrict__ Cout, int bx) {
    __shared__ unsigned short As[32 * 264];
    const int tid = threadIdx.x;
    const int lane = tid & 63, w = tid >> 6;
    const int l15 = lane & 15, quad = lane >> 4;
    const int r0 = (bx >> 1) * 32;
    const int c0w = (bx & 1) * 128 + w * 32;
    short8 wf[8][2];
#pragma unroll
    for (int kc = 0; kc < 8; ++kc)
#pragma unroll
        for (int dt = 0; dt < 2; ++dt)
            wf[kc][dt] = *(const short8*)(WT + (size_t)(c0w + dt * 16 + l15) * DD + kc * 32 + 8 * quad);
    fx4 bb[2];
#pragma unroll
    for (int dt = 0; dt < 2; ++dt)
        bb[dt] = *(const fx4*)(bias + c0w + dt * 16 + 4 * quad);
    stage_a32(Ain, As, r0, tid);
    __syncthreads();
    fx4 acc[2][2];
#pragma unroll
    for (int mt = 0; mt < 2; ++mt)
#pragma unroll
        for (int dt = 0; dt < 2; ++dt) acc[mt][dt] = (fx4){0.f, 0.f, 0.f, 0.f};
#pragma unroll
    for (int kc = 0; kc < 8; ++kc) {
        short8 a0 = *(const short8*)(As + l15 * 264 + kc * 32 + 8 * quad);
        short8 a1 = *(const short8*)(As + (16 + l15) * 264 + kc * 32 + 8 * quad);
#pragma unroll
        for (int dt = 0; dt < 2; ++dt) {
            acc[0][dt] = __builtin_amdgcn_mfma_f32_16x16x32_bf16(wf[kc][dt], a0, acc[0][dt], 0, 0, 0);
            acc[1][dt] = __builtin_amdgcn_mfma_f32_16x16x32_bf16(wf[kc][dt], a1, acc[1][dt], 0, 0, 0);
        }
    }
#pragma unroll
    for (int mt = 0; mt < 2; ++mt) {
        const size_t grow = r0 + mt * 16 + l15;
#pragma unroll
        for (int dt = 0; dt < 2; ++dt) {
            shortx4 pk;
#pragma unroll
            for (int r = 0; r < 4; ++r) pk[r] = (short)f2bf(acc[mt][dt][r] + bb[dt][r]);
            *(shortx4*)(Cout + grow * DD + c0w + dt * 16 + 4 * quad) = pk;
        }
    }
}

// ---------------------------------------------------------------------------
// Fused K+V projection: stage K once; pass 1 -> KT (transposed acc),
// pass 2 -> VT2 (original order). Register lifetimes disjoint.
// ---------------------------------------------------------------------------
__device__ __forceinline__ void kv_body(
        const float* __restrict__ Kin, const unsigned short* __restrict__ WTk,
        const unsigned short* __restrict__ WTv,
        const float* __restrict__ bk, const float* __restrict__ bvv,
        unsigned short* __restrict__ KT, unsigned short* __restrict__ VT2, int bx) {
    __shared__ unsigned short As[32 * 264];
    const int tid = threadIdx.x;
    const int lane = tid & 63, w = tid >> 6;
    const int l15 = lane & 15, quad = lane >> 4;
    const int r0 = (bx >> 1) * 32;
    const int c0w = (bx & 1) * 128 + w * 32;
    const int tl = (r0 & 2047) >> 5;
    const int b  = r0 >> 11;
    stage_a32(Kin, As, r0, tid);
    __syncthreads();
    {   // ---- pass 1: K -> KT (transposed acc, mfma(wf, a)) ----
        short8 wf[8][2];
#pragma unroll
        for (int kc = 0; kc < 8; ++kc)
#pragma unroll
            for (int dt = 0; dt < 2; ++dt)
                wf[kc][dt] = *(const short8*)(WTk + (size_t)(c0w + dt * 16 + l15) * DD + kc * 32 + 8 * quad);
        fx4 bb[2];
#pragma unroll
        for (int dt = 0; dt < 2; ++dt)
            bb[dt] = *(const fx4*)(bk + c0w + dt * 16 + 4 * quad);
        fx4 acc[2][2];
#pragma unroll
        for (int mt = 0; mt < 2; ++mt)
#pragma unroll
            for (int dt = 0; dt < 2; ++dt) acc[mt][dt] = (fx4){0.f, 0.f, 0.f, 0.f};
#pragma unroll
        for (int kc = 0; kc < 8; ++kc) {
            short8 a0 = *(const short8*)(As + l15 * 264 + kc * 32 + 8 * quad);
            short8 a1 = *(const short8*)(As + (16 + l15) * 264 + kc * 32 + 8 * quad);
#pragma unroll
            for (int dt = 0; dt < 2; ++dt) {
                acc[0][dt] = __builtin_amdgcn_mfma_f32_16x16x32_bf16(wf[kc][dt], a0, acc[0][dt], 0, 0, 0);
                acc[1][dt] = __builtin_amdgcn_mfma_f32_16x16x32_bf16(wf[kc][dt], a1, acc[1][dt], 0, 0, 0);
            }
        }
        // KT: col = c0w+dt*16+4*quad+r (d), key = mt*16+l15
#pragma unroll
        for (int mt = 0; mt < 2; ++mt) {
            const int key32 = mt * 16 + l15;
#pragma unroll
            for (int dt = 0; dt < 2; ++dt) {
                const int col = c0w + dt * 16 + 4 * quad;
                shortx4 pk;
#pragma unroll
                for (int r = 0; r < 4; ++r) pk[r] = (short)f2bf(acc[mt][dt][r] + bb[dt][r]);
                unsigned short* dstp = KT
                    + ((size_t)((b * 4 + (col >> 6)) * 64 + tl)) * 2048
                    + ((col >> 5) & 1) * 1024 + key32 * 32 + (col & 31);
                *(shortx4*)dstp = pk;
            }
        }
    }
    {   // ---- pass 2: K -> VT2 (original order, mfma(a, wf)) ----
        short8 wf[8][2];
#pragma unroll
        for (int kc = 0; kc < 8; ++kc)
#pragma unroll
            for (int dt = 0; dt < 2; ++dt)
                wf[kc][dt] = *(const short8*)(WTv + (size_t)(c0w + dt * 16 + l15) * DD + kc * 32 + 8 * quad);
        float bv[2];
#pragma unroll
        for (int dt = 0; dt < 2; ++dt) bv[dt] = bvv[c0w + dt * 16 + l15];
        fx4 acc[2][2];
#pragma unroll
        for (int mt = 0; mt < 2; ++mt)
#pragma unroll
            for (int dt = 0; dt < 2; ++dt) acc[mt][dt] = (fx4){0.f, 0.f, 0.f, 0.f};
#pragma unroll
        for (int kc = 0; kc < 8; ++kc) {
            short8 a0 = *(const short8*)(As + l15 * 264 + kc * 32 + 8 * quad);
            short8 a1 = *(const short8*)(As + (16 + l15) * 264 + kc * 32 + 8 * quad);
#pragma unroll
            for (int dt = 0; dt < 2; ++dt) {
                acc[0][dt] = __builtin_amdgcn_mfma_f32_16x16x32_bf16(a0, wf[kc][dt], acc[0][dt], 0, 0, 0);
                acc[1][dt] = __builtin_amdgcn_mfma_f32_16x16x32_bf16(a1, wf[kc][dt], acc[1][dt], 0, 0, 0);
            }
        }
        // VT2: key = r0+mt*16+4*quad+r, col = c0w+dt*16+l15 (d)
#pragma unroll
        for (int mt = 0; mt < 2; ++mt) {
#pragma unroll
            for (int dt = 0; dt < 2; ++dt) {
                const int col = c0w + dt * 16 + l15;
                shortx4 pk;
#pragma unroll
                for (int r = 0; r < 4; ++r) pk[r] = (short)f2bf(acc[mt][dt][r] + bv[dt]);
                unsigned short* dstp = VT2
                    + ((size_t)((b * 4 + (col >> 6)) * 64 + tl)) * 2048
                    + (col & 63) * 32 + mt * 16 + 4 * quad;
                *(shortx4*)dstp = pk;
            }
        }
    }
}

// Fused QKV projections: grid (512, 2); y=0: Q->Qp, y=1: K->{KT,VT2}.
__global__ __launch_bounds__(256, 4) void qkv_mfma(
        const float* __restrict__ Q, const float* __restrict__ K,
        const unsigned short* __restrict__ WT5,
        const float* __restrict__ bq, const float* __restrict__ bk,
        const float* __restrict__ bv,
        unsigned short* __restrict__ Qp, unsigned short* __restrict__ KT,
        unsigned short* __restrict__ VT2) {
    if (blockIdx.y == 0) q_body(Q, WT5, bq, Qp, blockIdx.x);
    else kv_body(K, WT5 + 65536, WT5 + 131072, bk, bv, KT, VT2, blockIdx.x);
}

// ---------------------------------------------------------------------------
// Flash attention, O^T form, no-max softmax. r20: 2 q-subtiles per wave.
// Block = 128 q-rows x 512 keys (kq quarter), grid 1024 (4 blocks/CU).
// 4 waves x 32 q-rows each; per tile: read ck/cv ONCE, run QK+softmax+PV
// for both q-subtiles (16 MFMA/tile/wave). Double-buffered XOR-swizzled LDS.
// Unnormalized partials Od[kq], Lp[kq]; merge in ffn_fused.
// ---------------------------------------------------------------------------
__global__ __launch_bounds__(256, 2) void attn_mfma(
        const unsigned short* __restrict__ Qp, const unsigned short* __restrict__ KT,
        const unsigned short* __restrict__ VT2, float* __restrict__ Od,
        float* __restrict__ Lp) {
    __shared__ unsigned short kbuf[2][2048];  // K tile double buffer (4KB ea)
    __shared__ unsigned short vbuf[2][2048];  // V tile double buffer
    __shared__ unsigned int pbuf[4][256];     // per-wave P exchange, pitch 16 dw
    const int tid = threadIdx.x;
    const int lane = tid & 63, w = tid >> 6;  // w = wave (32 q-rows each)
    const int l15 = lane & 15, quad = lane >> 4;
    const int gb = blockIdx.x;                // 0..1023
    const int bh = ((gb & 7) << 1) | ((gb >> 9) & 1);   // XCD-locality swizzle
    const int qc = (gb >> 3) & 15;
    const int kq = (gb >> 7) & 3;                       // key quarter
    const int h  = bh & 3;
    const int b  = bh >> 2;
    const int qrow = qc * 128 + w * 32;
    const int sw = 4 * ((l15 >> 1) & 3);                // pbuf bank swizzle

    short8 aq0, aq1, aq2, aq3;
    {
        const unsigned short* qptr = Qp + ((size_t)(b * NN + qrow + l15) * DD + h * DHH + 8 * quad);
        aq0 = *(const short8*)qptr;
        aq1 = *(const short8*)(qptr + 32);
        const unsigned short* qptr2 = qptr + (size_t)16 * DD;
        aq2 = *(const short8*)qptr2;
        aq3 = *(const short8*)(qptr2 + 32);
    }
    fx4 od00 = (fx4){0.f, 0.f, 0.f, 0.f};
    fx4 od01 = (fx4){0.f, 0.f, 0.f, 0.f};
    fx4 od02 = (fx4){0.f, 0.f, 0.f, 0.f};
    fx4 od03 = (fx4){0.f, 0.f, 0.f, 0.f};
    fx4 od10 = (fx4){0.f, 0.f, 0.f, 0.f};
    fx4 od11 = (fx4){0.f, 0.f, 0.f, 0.f};
    fx4 od12 = (fx4){0.f, 0.f, 0.f, 0.f};
    fx4 od13 = (fx4){0.f, 0.f, 0.f, 0.f};
    float lsum0 = 0.0f, lsum1 = 0.0f;

    unsigned int* pw = &pbuf[w][0];
    const int wcol = (2 * quad) ^ sw;         // write cols (pairs t=2q,2q+1 / +8)
    const int rcol = (4 * quad) ^ sw;         // read col group (t=4Q..4Q+3)
    const unsigned short* ktb = KT  + (size_t)(bh * 64 + kq * 16) * 2048 + tid * 8;
    const unsigned short* vtb = VT2 + (size_t)(bh * 64 + kq * 16) * 2048 + tid * 8;
    // K/V tile swizzle: element e -> e ^ (((e>>6)&3)<<3)  (byte[5:4]^=byte[8:7])
    const int ew = (tid * 8) ^ (((tid >> 3) & 3) << 3);          // stage-write dst
    const int fo = (l15 * 32 + 8 * quad) ^ (((l15 >> 1) & 3) << 3); // frag-read base

    // prologue: stage tile 0 into buffer 0
    {
        uint4v kr = *(const uint4v*)ktb;
        uint4v vr = *(const uint4v*)vtb;
        *(uint4v*)&kbuf[0][ew] = kr;
        *(uint4v*)&vbuf[0][ew] = vr;
    }
    __syncthreads();

    for (int t = 0; t < 16; ++t) {
        const int cur = t & 1;
        const int tn = (t < 15) ? t + 1 : 15;           // clamp (last redundant)
        // issue next-tile global loads FIRST (T14 async split: write after compute)
        uint4v kr = *(const uint4v*)(ktb + (size_t)tn * 2048);
        uint4v vr = *(const uint4v*)(vtb + (size_t)tn * 2048);

        // ---- compute tile t from LDS (frags read ONCE for 2 q-subtiles) ----
        const unsigned short* kb = &kbuf[cur][fo];
        short8 ck0 = *(const short8*)(kb);          // keys l15,    d 8q..8q+7
        short8 ck1 = *(const short8*)(kb + 1024);   // keys l15,    d 32+8q..
        short8 ck2 = *(const short8*)(kb + 512);    // keys 16+l15, d 8q..
        short8 ck3 = *(const short8*)(kb + 1536);   // keys 16+l15, d 32+8q..
        const unsigned short* vb = &vbuf[cur][fo];
        short8 cv0 = *(const short8*)(vb);          // d l15,    keys 8q..8q+7
        short8 cv1 = *(const short8*)(vb + 512);    // d 16+l15
        short8 cv2 = *(const short8*)(vb + 1024);   // d 32+l15
        short8 cv3 = *(const short8*)(vb + 1536);   // d 48+l15

        const fx4 z_ = (fx4){0.f, 0.f, 0.f, 0.f};
        // QK^T both subtiles
        fx4 s0 = __builtin_amdgcn_mfma_f32_16x16x32_bf16(ck0, aq0, z_, 0, 0, 0);
        s0     = __builtin_amdgcn_mfma_f32_16x16x32_bf16(ck1, aq1, s0, 0, 0, 0);
        fx4 s1 = __builtin_amdgcn_mfma_f32_16x16x32_bf16(ck2, aq0, z_, 0, 0, 0);
        s1     = __builtin_amdgcn_mfma_f32_16x16x32_bf16(ck3, aq1, s1, 0, 0, 0);
        fx4 s2 = __builtin_amdgcn_mfma_f32_16x16x32_bf16(ck0, aq2, z_, 0, 0, 0);
        s2     = __builtin_amdgcn_mfma_f32_16x16x32_bf16(ck1, aq3, s2, 0, 0, 0);
        fx4 s3 = __builtin_amdgcn_mfma_f32_16x16x32_bf16(ck2, aq2, z_, 0, 0, 0);
        s3     = __builtin_amdgcn_mfma_f32_16x16x32_bf16(ck3, aq3, s3, 0, 0, 0);
        s0[0] = __expf(s0[0] * 0.125f); s0[1] = __expf(s0[1] * 0.125f);
        s0[2] = __expf(s0[2] * 0.125f); s0[3] = __expf(s0[3] * 0.125f);
        s1[0] = __expf(s1[0] * 0.125f); s1[1] = __expf(s1[1] * 0.125f);
        s1[2] = __expf(s1[2] * 0.125f); s1[3] = __expf(s1[3] * 0.125f);
        s2[0] = __expf(s2[0] * 0.125f); s2[1] = __expf(s2[1] * 0.125f);
        s2[2] = __expf(s2[2] * 0.125f); s2[3] = __expf(s2[3] * 0.125f);
        s3[0] = __expf(s3[0] * 0.125f); s3[1] = __expf(s3[1] * 0.125f);
        s3[2] = __expf(s3[2] * 0.125f); s3[3] = __expf(s3[3] * 0.125f);
        lsum0 += s0[0] + s0[1] + s0[2] + s0[3] + s1[0] + s1[1] + s1[2] + s1[3];
        lsum1 += s2[0] + s2[1] + s2[2] + s2[3] + s3[0] + s3[1] + s3[2] + s3[3];
        // exchange + PV, subtile 0
        {
            uint2v w1_ = (uint2v){packbf(s0[0], s0[1]), packbf(s0[2], s0[3])};
            uint2v w2_ = (uint2v){packbf(s1[0], s1[1]), packbf(s1[2], s1[3])};
            *(uint2v*)(pw + l15 * 16 + wcol)       = w1_;
            *(uint2v*)(pw + l15 * 16 + (wcol ^ 8)) = w2_;
            short8 bp = *(const short8*)(pw + l15 * 16 + rcol);
            od00 = __builtin_amdgcn_mfma_f32_16x16x32_bf16(cv0, bp, od00, 0, 0, 0);
            od01 = __builtin_amdgcn_mfma_f32_16x16x32_bf16(cv1, bp, od01, 0, 0, 0);
            od02 = __builtin_amdgcn_mfma_f32_16x16x32_bf16(cv2, bp, od02, 0, 0, 0);
            od03 = __builtin_amdgcn_mfma_f32_16x16x32_bf16(cv3, bp, od03, 0, 0, 0);
        }
        // exchange + PV, subtile 1 (same pbuf region, wave-sequential)
        {
            uint2v w1_ = (uint2v){packbf(s2[0], s2[1]), packbf(s2[2], s2[3])};
            uint2v w2_ = (uint2v){packbf(s3[0], s3[1]), packbf(s3[2], s3[3])};
            *(uint2v*)(pw + l15 * 16 + wcol)       = w1_;
            *(uint2v*)(pw + l15 * 16 + (wcol ^ 8)) = w2_;
            short8 bp = *(const short8*)(pw + l15 * 16 + rcol);
            od10 = __builtin_amdgcn_mfma_f32_16x16x32_bf16(cv0, bp, od10, 0, 0, 0);
            od11 = __builtin_amdgcn_mfma_f32_16x16x32_bf16(cv1, bp, od11, 0, 0, 0);
            od12 = __builtin_amdgcn_mfma_f32_16x16x32_bf16(cv2, bp, od12, 0, 0, 0);
            od13 = __builtin_amdgcn_mfma_f32_16x16x32_bf16(cv3, bp, od13, 0, 0, 0);
        }

        // ---- land next tile into the other buffer, then sync ----
        *(uint4v*)&kbuf[cur ^ 1][ew] = kr;
        *(uint4v*)&vbuf[cur ^ 1][ew] = vr;
        __syncthreads();
    }

    // per-q partial l (sum over quads); write UNNORMALIZED partials
    lsum0 += __shfl_xor(lsum0, 16);
    lsum0 += __shfl_xor(lsum0, 32);
    lsum1 += __shfl_xor(lsum1, 16);
    lsum1 += __shfl_xor(lsum1, 32);
    const size_t grow0 = (size_t)(b * NN) + qrow + l15;
    const size_t grow1 = grow0 + 16;
    float* ob0 = Od + (size_t)kq * 2097152 + grow0 * DD + h * DHH;
    *(fx4*)(ob0 + 0 * 16 + 4 * quad) = od00;
    *(fx4*)(ob0 + 1 * 16 + 4 * quad) = od01;
    *(fx4*)(ob0 + 2 * 16 + 4 * quad) = od02;
    *(fx4*)(ob0 + 3 * 16 + 4 * quad) = od03;
    float* ob1 = Od + (size_t)kq * 2097152 + grow1 * DD + h * DHH;
    *(fx4*)(ob1 + 0 * 16 + 4 * quad) = od10;
    *(fx4*)(ob1 + 1 * 16 + 4 * quad) = od11;
    *(fx4*)(ob1 + 2 * 16 + 4 * quad) = od12;
    *(fx4*)(ob1 + 3 * 16 + 4 * quad) = od13;
    if (quad == 0) {
        Lp[(size_t)kq * 32768 + grow0 * 4 + h] = lsum0;
        Lp[(size_t)kq * 32768 + grow1 * 4 + h] = lsum1;
    }
}

// ---------------------------------------------------------------------------
// Fused FFN: merge(Od)/l + Qp residual + LN0 -> O (fp32 global, phase-3
// residual) + As (bf16); ffn1 MFMA -> relu -> Hs (LDS only); ffn2 MFMA ->
// +b2 + O -> LN1 -> out. Block = 32 rows, 512 thr, 8 waves (32 cols each).
// ---------------------------------------------------------------------------
__global__ __launch_bounds__(512) void ffn_fused(
        const float* __restrict__ Od, const float* __restrict__ Lp,
        const unsigned short* __restrict__ Qp,
        const float* __restrict__ g0, const float* __restrict__ be0,
        const unsigned short* __restrict__ WT1, const float* __restrict__ b1,
        const unsigned short* __restrict__ WT2, const float* __restrict__ b2,
        const float* __restrict__ g1, const float* __restrict__ be1,
        float* __restrict__ O, float* __restrict__ out) {
    __shared__ unsigned short As[32 * 264];   // LN0(O) bf16 (ffn1 A)
    __shared__ unsigned short Hs[32 * 264];   // H1 bf16 (ffn2 A)
    __shared__ float lnb[2][8][32];
    const int tid = threadIdx.x;
    const int lane = tid & 63, w = tid >> 6;          // w in 0..7
    const int l15 = lane & 15, quad = lane >> 4;
    const int r0 = blockIdx.x * 32;
    const int c0w = w * 32;
    {   // ---- phase 1: merge + residual + LN0; row = tid>>4, 16 elems ----
        const int row = tid >> 4, c0 = (tid & 15) * 16;
        const size_t grow = r0 + row;
        const int hh = c0 >> 6;
        const float inv = 1.0f / (Lp[grow * 4 + hh] + Lp[32768 + grow * 4 + hh]
                                + Lp[65536 + grow * 4 + hh] + Lp[98304 + grow * 4 + hh]);
        float v[16];
        float s1 = 0.f, s2 = 0.f;
        const float* odp = Od + grow * DD + c0;
#pragma unroll
        for (int j = 0; j < 4; ++j) {
            fx4 m0 = *(const fx4*)(odp + j * 4);
            fx4 m1 = *(const fx4*)(odp + 2097152 + j * 4);
            fx4 m2 = *(const fx4*)(odp + 4194304 + j * 4);
            fx4 m3 = *(const fx4*)(odp + 6291456 + j * 4);
            shortx4 qv = *(const shortx4*)(Qp + grow * DD + c0 + j * 4);
#pragma unroll
            for (int i = 0; i < 4; ++i) {
                float x = (m0[i] + m1[i] + m2[i] + m3[i]) * inv
                        + bf2f((unsigned short)qv[i]);
                v[j * 4 + i] = x; s1 += x; s2 += x * x;
            }
        }
        s1 += __shfl_xor(s1, 1); s2 += __shfl_xor(s2, 1);
        s1 += __shfl_xor(s1, 2); s2 += __shfl_xor(s2, 2);
        s1 += __shfl_xor(s1, 4); s2 += __shfl_xor(s2, 4);
        s1 += __shfl_xor(s1, 8); s2 += __shfl_xor(s2, 8);
        const float mean = s1 * (1.0f / 256.0f);
        const float var  = s2 * (1.0f / 256.0f) - mean * mean;
        const float rstd = rsqrtf(var + 1e-5f);
#pragma unroll
        for (int j = 0; j < 4; ++j) {
            fx4 gg = *(const fx4*)(g0 + c0 + j * 4);
            fx4 ee = *(const fx4*)(be0 + c0 + j * 4);
            fx4 o; shortx4 ob;
#pragma unroll
            for (int i = 0; i < 4; ++i) {
                o[i] = (v[j * 4 + i] - mean) * rstd * gg[i] + ee[i];
                ob[i] = (short)f2bf(o[i]);
            }
            *(fx4*)(O + grow * DD + c0 + j * 4) = o;
            *(shortx4*)(As + row * 264 + c0 + j * 4) = ob;
        }
    }
    // W1 frags + b1
    short8 wf[8][2];
#pragma unroll
    for (int kc = 0; kc < 8; ++kc)
#pragma unroll
        for (int dt = 0; dt < 2; ++dt)
            wf[kc][dt] = *(const short8*)(WT1 + (size_t)(c0w + dt * 16 + l15) * DD + kc * 32 + 8 * quad);
    fx4 bb1[2];
#pragma unroll
    for (int dt = 0; dt < 2; ++dt)
        bb1[dt] = *(const fx4*)(b1 + c0w + dt * 16 + 4 * quad);
    __syncthreads();
    // ---- phase 2: ffn1 MFMA -> relu -> Hs ----
    fx4 acc[2][2];
#pragma unroll
    for (int mt = 0; mt < 2; ++mt)
#pragma unroll
        for (int dt = 0; dt < 2; ++dt) acc[mt][dt] = (fx4){0.f, 0.f, 0.f, 0.f};
#pragma unroll
    for (int kc = 0; kc < 8; ++kc) {
        short8 a0 = *(const short8*)(As + l15 * 264 + kc * 32 + 8 * quad);
        short8 a1 = *(const short8*)(As + (16 + l15) * 264 + kc * 32 + 8 * quad);
#pragma unroll
        for (int dt = 0; dt < 2; ++dt) {
            acc[0][dt] = __builtin_amdgcn_mfma_f32_16x16x32_bf16(wf[kc][dt], a0, acc[0][dt], 0, 0, 0);
            acc[1][dt] = __builtin_amdgcn_mfma_f32_16x16x32_bf16(wf[kc][dt], a1, acc[1][dt], 0, 0, 0);
        }
    }
#pragma unroll
    for (int mt = 0; mt < 2; ++mt) {
#pragma unroll
        for (int dt = 0; dt < 2; ++dt) {
            shortx4 pk;
#pragma unroll
            for (int r = 0; r < 4; ++r)
                pk[r] = (short)f2bf(fmaxf(acc[mt][dt][r] + bb1[dt][r], 0.0f));
            *(shortx4*)(Hs + (mt * 16 + l15) * 264 + c0w + dt * 16 + 4 * quad) = pk;
        }
    }
    // W2 frags + b2 + g1/be1
    short8 wf2[8][2];
#pragma unroll
    for (int kc = 0; kc < 8; ++kc)
#pragma unroll
        for (int dt = 0; dt < 2; ++dt)
            wf2[kc][dt] = *(const short8*)(WT2 + (size_t)(c0w + dt * 16 + l15) * DD + kc * 32 + 8 * quad);
    fx4 bb2[2], gg1[2], ee1[2];
#pragma unroll
    for (int dt = 0; dt < 2; ++dt) {
        int col = c0w + dt * 16 + 4 * quad;
        bb2[dt] = *(const fx4*)(b2 + col);
        gg1[dt] = *(const fx4*)(g1 + col);
        ee1[dt] = *(const fx4*)(be1 + col);
    }
    __syncthreads();
    // ---- phase 3: ffn2 MFMA -> +b2 + O residual -> LN1 -> out ----
    fx4 acc2[2][2];
#pragma unroll
    for (int mt = 0; mt < 2; ++mt)
#pragma unroll
        for (int dt = 0; dt < 2; ++dt) acc2[mt][dt] = (fx4){0.f, 0.f, 0.f, 0.f};
#pragma unroll
    for (int kc = 0; kc < 8; ++kc) {
        short8 a0 = *(const short8*)(Hs + l15 * 264 + kc * 32 + 8 * quad);
        short8 a1 = *(const short8*)(Hs + (16 + l15) * 264 + kc * 32 + 8 * quad);
#pragma unroll
        for (int dt = 0; dt < 2; ++dt) {
            acc2[0][dt] = __builtin_amdgcn_mfma_f32_16x16x32_bf16(wf2[kc][dt], a0, acc2[0][dt], 0, 0, 0);
            acc2[1][dt] = __builtin_amdgcn_mfma_f32_16x16x32_bf16(wf2[kc][dt], a1, acc2[1][dt], 0, 0, 0);
        }
    }
    fx4 v4[2][2];
#pragma unroll
    for (int mt = 0; mt < 2; ++mt) {
        const size_t grow = r0 + mt * 16 + l15;
        float p1 = 0.f, p2 = 0.f;
#pragma unroll
        for (int dt = 0; dt < 2; ++dt) {
            fx4 rv = *(const fx4*)(O + grow * DD + c0w + dt * 16 + 4 * quad);
#pragma unroll
            for (int r = 0; r < 4; ++r) {
                float x = acc2[mt][dt][r] + bb2[dt][r] + rv[r];
                v4[mt][dt][r] = x; p1 += x; p2 += x * x;
            }
        }
        p1 += __shfl_xor(p1, 16); p2 += __shfl_xor(p2, 16);
        p1 += __shfl_xor(p1, 32); p2 += __shfl_xor(p2, 32);
        if (quad == 0) { lnb[0][w][mt * 16 + l15] = p1; lnb[1][w][mt * 16 + l15] = p2; }
    }
    __syncthreads();
#pragma unroll
    for (int mt = 0; mt < 2; ++mt) {
        const int row = mt * 16 + l15;
        float s1 = 0.f, s2 = 0.f;
#pragma unroll
        for (int ww = 0; ww < 8; ++ww) { s1 += lnb[0][ww][row]; s2 += lnb[1][ww][row]; }
        const float mean = s1 * (1.0f / 256.0f);
        const float var  = s2 * (1.0f / 256.0f) - mean * mean;
        const float rstd = rsqrtf(var + 1e-5f);
        const size_t grow = r0 + row;
#pragma unroll
        for (int dt = 0; dt < 2; ++dt) {
            fx4 o;
#pragma unroll
            for (int r = 0; r < 4; ++r)
                o[r] = (v4[mt][dt][r] - mean) * rstd * gg1[dt][r] + ee1[dt][r];
            *(fx4*)(out + grow * DD + c0w + dt * 16 + 4 * quad) = o;
        }
    }
}

extern "C" void kernel_launch(void* const* d_in, const int* in_sizes, int n_in,
                              void* d_out, int out_size, void* d_ws, size_t ws_size,
                              hipStream_t stream) {
    (void)in_sizes; (void)n_in; (void)out_size; (void)ws_size;
    const float* Q     = (const float*)d_in[0];
    const float* K     = (const float*)d_in[1];
    const float* Wq    = (const float*)d_in[2];
    const float* bq    = (const float*)d_in[3];
    const float* Wk    = (const float*)d_in[4];
    const float* bk    = (const float*)d_in[5];
    const float* Wv    = (const float*)d_in[6];
    const float* bv    = (const float*)d_in[7];
    const float* W1    = (const float*)d_in[8];
    const float* b1    = (const float*)d_in[9];
    const float* W2    = (const float*)d_in[10];
    const float* b2    = (const float*)d_in[11];
    const float* g0    = (const float*)d_in[12];
    const float* beta0 = (const float*)d_in[13];
    const float* g1    = (const float*)d_in[14];
    const float* beta1 = (const float*)d_in[15];

    // Workspace: [0,4)Mi Qp bf16; [4,8)Mi KT; [8,12)Mi VT2; [12,44)Mi Od[4];
    // [44,52)Mi O f32; [52,+512K) Lp; [53Mi,+640K) WT x5
    char* ws = (char*)d_ws;
    unsigned short* Qp  = (unsigned short*)(ws);
    unsigned short* KT  = (unsigned short*)(ws + (4u  << 20));
    unsigned short* VT2 = (unsigned short*)(ws + (8u  << 20));
    float*          Od  = (float*)(ws + (12u << 20));   // 4 x 8MB partials
    float*          O   = (float*)(ws + (44u << 20));
    float*          Lp  = (float*)(ws + (52u << 20));
    unsigned short* WT5 = (unsigned short*)(ws + (53u << 20));
    float*          out = (float*)d_out;

    const unsigned short* WT1 = WT5 + 3 * 65536;
    const unsigned short* WT2 = WT5 + 4 * 65536;

    const int M = BB * NN;                        // 8192 rows

    wt_prep<<<dim3(4, 4, 5), 256, 0, stream>>>(Wq, Wk, Wv, W1, W2, WT5);
    qkv_mfma<<<dim3(M / 16, 2), 256, 0, stream>>>(Q, K, WT5, bq, bk, bv, Qp, KT, VT2);
    attn_mfma<<<1024, 256, 0, stream>>>(Qp, KT, VT2, Od, Lp);
    ffn_fused<<<M / 32, 512, 0, stream>>>(Od, Lp, Qp, g0, beta0, WT1, b1,
                                          WT2, b2, g1, beta1, O, out);
}

// Round 15
// 158.728 us; speedup vs baseline: 1.1342x; 1.0208x over previous
//
#include <hip/hip_runtime.h>

// MAB block, MFMA bf16, round 21: keep ffn's O entirely in LDS.
// r20 post-mortem: non-attn time constant ~134us across ALL rounds despite
// massive restructuring; the only top-5 dispatches are 268MB harness
// workspace-poison fills at 43-47us each (71-79% HBM peak) -> ~2-3 timed
// fills/iteration = ~130us fixed overhead; controllable kernel time ~30us.
// r21 removes the last known pure waste: ffn_fused wrote O (8MB fp32) to
// global in phase 1 and read it back in phase 3 -- same block, same rows,
// barrier already present. Move to LDS (Osh[32][260], <=2-way conflicts).
// 16MB global round-trip eliminated; arithmetic bit-identical.

typedef float fx4 __attribute__((ext_vector_type(4)));
typedef short short8 __attribute__((ext_vector_type(8)));
typedef short shortx4 __attribute__((ext_vector_type(4)));
typedef unsigned int uint2v __attribute__((ext_vector_type(2)));
typedef unsigned int uint4v __attribute__((ext_vector_type(4)));

#define BB  4
#define NN  2048
#define DD  256
#define HH  4
#define DHH 64

__device__ __forceinline__ float bf2f(unsigned short u) {
    union { unsigned int i; float f; } v; v.i = ((unsigned int)u) << 16; return v.f;
}
__device__ __forceinline__ unsigned short f2bf(float f) {
    union { float f; unsigned int i; } v; v.f = f;
    unsigned int r = v.i + 0x7FFF + ((v.i >> 16) & 1);   // RNE
    return (unsigned short)(r >> 16);
}
__device__ __forceinline__ unsigned int fbits(float f) {
    union { float f; unsigned int i; } v; v.f = f; return v.i;
}
__device__ __forceinline__ unsigned int packbf(float lo, float hi) {
    unsigned int a = fbits(lo), b = fbits(hi);
    a = (a + 0x7FFF + ((a >> 16) & 1)) >> 16;
    b = (b + 0x7FFF + ((b >> 16) & 1)) & 0xFFFF0000u;
    return a | b;
}

// ---------------------------------------------------------------------------
// Weight prep: WT[n][k] = bf16(W[k][n]) for the 5 weight matrices (256x256).
// ---------------------------------------------------------------------------
__global__ __launch_bounds__(256) void wt_prep(
        const float* __restrict__ w0, const float* __restrict__ w1,
        const float* __restrict__ w2, const float* __restrict__ w3,
        const float* __restrict__ w4, unsigned short* __restrict__ dst) {
    __shared__ unsigned short T[64 * 73];
    const int tid = threadIdx.x;
    const int z = blockIdx.z;
    const float* W = (z == 0) ? w0 : (z == 1) ? w1 : (z == 2) ? w2 : (z == 3) ? w3 : w4;
    unsigned short* WT = dst + z * 65536;
    const int nb = blockIdx.x * 64, kb = blockIdx.y * 64;
    {
        int kl = tid >> 2, c0 = (tid & 3) * 16;
        const float* src = W + (size_t)(kb + kl) * DD + nb + c0;
#pragma unroll
        for (int i = 0; i < 16; ++i) T[kl * 73 + c0 + i] = f2bf(src[i]);
    }
    __syncthreads();
    {
        int nl = tid >> 2, k0 = (tid & 3) * 16;
        short8 o0, o1;
#pragma unroll
        for (int i = 0; i < 8; ++i) {
            o0[i] = (short)T[(k0 + i) * 73 + nl];
            o1[i] = (short)T[(k0 + 8 + i) * 73 + nl];
        }
        short8* d = (short8*)(WT + (size_t)(nb + nl) * DD + kb + k0);
        d[0] = o0; d[1] = o1;
    }
}

// ---------------------------------------------------------------------------
// Shared A-staging: 32x256 fp32 -> bf16 into As (pitch 264).
// ---------------------------------------------------------------------------
__device__ __forceinline__ void stage_a32(
        const float* __restrict__ Ain, unsigned short* __restrict__ As,
        int r0, int tid) {
    int row = tid >> 3, c0 = (tid & 7) * 32;
    short8 o[4];
    const fx4* s4 = (const fx4*)(Ain + (size_t)(r0 + row) * DD + c0);
#pragma unroll
    for (int j = 0; j < 4; ++j) {
        fx4 v0 = s4[2 * j], v1 = s4[2 * j + 1];
#pragma unroll
        for (int i = 0; i < 4; ++i) {
            o[j][i]     = (short)f2bf(v0[i]);
            o[j][i + 4] = (short)f2bf(v1[i]);
        }
    }
    short8* d = (short8*)(As + row * 264 + c0);
#pragma unroll
    for (int j = 0; j < 4; ++j) d[j] = o[j];
}

// ---------------------------------------------------------------------------
// Q projection: row-major Qp (transposed acc, mfma(wf,a)). 32-row tile.
// ---------------------------------------------------------------------------
__device__ __forceinline__ void q_body(
        const float* __restrict__ Ain, const unsigned short* __restrict__ WT,
        const float* __restrict__ bias, unsigned short* __restrict__ Cout, int bx) {
    __shared__ unsigned short As[32 * 264];
    const int tid = threadIdx.x;
    const int lane = tid & 63, w = tid >> 6;
    const int l15 = lane & 15, quad = lane >> 4;
    const int r0 = (bx >> 1) * 32;
    const int c0w = (bx & 1) * 128 + w * 32;
    short8 wf[8][2];
#pragma unroll
    for (int kc = 0; kc < 8; ++kc)
#pragma unroll
        for (int dt = 0; dt < 2; ++dt)
            wf[kc][dt] = *(const short8*)(WT + (size_t)(c0w + dt * 16 + l15) * DD + kc * 32 + 8 * quad);
    fx4 bb[2];
#pragma unroll
    for (int dt = 0; dt < 2; ++dt)
        bb[dt] = *(const fx4*)(bias + c0w + dt * 16 + 4 * quad);
    stage_a32(Ain, As, r0, tid);
    __syncthreads();
    fx4 acc[2][2];
#pragma unroll
    for (int mt = 0; mt < 2; ++mt)
#pragma unroll
        for (int dt = 0; dt < 2; ++dt) acc[mt][dt] = (fx4){0.f, 0.f, 0.f, 0.f};
#pragma unroll
    for (int kc = 0; kc < 8; ++kc) {
        short8 a0 = *(const short8*)(As + l15 * 264 + kc * 32 + 8 * quad);
        short8 a1 = *(const short8*)(As + (16 + l15) * 264 + kc * 32 + 8 * quad);
#pragma unroll
        for (int dt = 0; dt < 2; ++dt) {
            acc[0][dt] = __builtin_amdgcn_mfma_f32_16x16x32_bf16(wf[kc][dt], a0, acc[0][dt], 0, 0, 0);
            acc[1][dt] = __builtin_amdgcn_mfma_f32_16x16x32_bf16(wf[kc][dt], a1, acc[1][dt], 0, 0, 0);
        }
    }
#pragma unroll
    for (int mt = 0; mt < 2; ++mt) {
        const size_t grow = r0 + mt * 16 + l15;
#pragma unroll
        for (int dt = 0; dt < 2; ++dt) {
            shortx4 pk;
#pragma unroll
            for (int r = 0; r < 4; ++r) pk[r] = (short)f2bf(acc[mt][dt][r] + bb[dt][r]);
            *(shortx4*)(Cout + grow * DD + c0w + dt * 16 + 4 * quad) = pk;
        }
    }
}

// ---------------------------------------------------------------------------
// Fused K+V projection: stage K once; pass 1 -> KT (transposed acc),
// pass 2 -> VT2 (original order). Register lifetimes disjoint.
// ---------------------------------------------------------------------------
__device__ __forceinline__ void kv_body(
        const float* __restrict__ Kin, const unsigned short* __restrict__ WTk,
        const unsigned short* __restrict__ WTv,
        const float* __restrict__ bk, const float* __restrict__ bvv,
        unsigned short* __restrict__ KT, unsigned short* __restrict__ VT2, int bx) {
    __shared__ unsigned short As[32 * 264];
    const int tid = threadIdx.x;
    const int lane = tid & 63, w = tid >> 6;
    const int l15 = lane & 15, quad = lane >> 4;
    const int r0 = (bx >> 1) * 32;
    const int c0w = (bx & 1) * 128 + w * 32;
    const int tl = (r0 & 2047) >> 5;
    const int b  = r0 >> 11;
    stage_a32(Kin, As, r0, tid);
    __syncthreads();
    {   // ---- pass 1: K -> KT (transposed acc, mfma(wf, a)) ----
        short8 wf[8][2];
#pragma unroll
        for (int kc = 0; kc < 8; ++kc)
#pragma unroll
            for (int dt = 0; dt < 2; ++dt)
                wf[kc][dt] = *(const short8*)(WTk + (size_t)(c0w + dt * 16 + l15) * DD + kc * 32 + 8 * quad);
        fx4 bb[2];
#pragma unroll
        for (int dt = 0; dt < 2; ++dt)
            bb[dt] = *(const fx4*)(bk + c0w + dt * 16 + 4 * quad);
        fx4 acc[2][2];
#pragma unroll
        for (int mt = 0; mt < 2; ++mt)
#pragma unroll
            for (int dt = 0; dt < 2; ++dt) acc[mt][dt] = (fx4){0.f, 0.f, 0.f, 0.f};
#pragma unroll
        for (int kc = 0; kc < 8; ++kc) {
            short8 a0 = *(const short8*)(As + l15 * 264 + kc * 32 + 8 * quad);
            short8 a1 = *(const short8*)(As + (16 + l15) * 264 + kc * 32 + 8 * quad);
#pragma unroll
            for (int dt = 0; dt < 2; ++dt) {
                acc[0][dt] = __builtin_amdgcn_mfma_f32_16x16x32_bf16(wf[kc][dt], a0, acc[0][dt], 0, 0, 0);
                acc[1][dt] = __builtin_amdgcn_mfma_f32_16x16x32_bf16(wf[kc][dt], a1, acc[1][dt], 0, 0, 0);
            }
        }
        // KT: col = c0w+dt*16+4*quad+r (d), key = mt*16+l15
#pragma unroll
        for (int mt = 0; mt < 2; ++mt) {
            const int key32 = mt * 16 + l15;
#pragma unroll
            for (int dt = 0; dt < 2; ++dt) {
                const int col = c0w + dt * 16 + 4 * quad;
                shortx4 pk;
#pragma unroll
                for (int r = 0; r < 4; ++r) pk[r] = (short)f2bf(acc[mt][dt][r] + bb[dt][r]);
                unsigned short* dstp = KT
                    + ((size_t)((b * 4 + (col >> 6)) * 64 + tl)) * 2048
                    + ((col >> 5) & 1) * 1024 + key32 * 32 + (col & 31);
                *(shortx4*)dstp = pk;
            }
        }
    }
    {   // ---- pass 2: K -> VT2 (original order, mfma(a, wf)) ----
        short8 wf[8][2];
#pragma unroll
        for (int kc = 0; kc < 8; ++kc)
#pragma unroll
            for (int dt = 0; dt < 2; ++dt)
                wf[kc][dt] = *(const short8*)(WTv + (size_t)(c0w + dt * 16 + l15) * DD + kc * 32 + 8 * quad);
        float bv[2];
#pragma unroll
        for (int dt = 0; dt < 2; ++dt) bv[dt] = bvv[c0w + dt * 16 + l15];
        fx4 acc[2][2];
#pragma unroll
        for (int mt = 0; mt < 2; ++mt)
#pragma unroll
            for (int dt = 0; dt < 2; ++dt) acc[mt][dt] = (fx4){0.f, 0.f, 0.f, 0.f};
#pragma unroll
        for (int kc = 0; kc < 8; ++kc) {
            short8 a0 = *(const short8*)(As + l15 * 264 + kc * 32 + 8 * quad);
            short8 a1 = *(const short8*)(As + (16 + l15) * 264 + kc * 32 + 8 * quad);
#pragma unroll
            for (int dt = 0; dt < 2; ++dt) {
                acc[0][dt] = __builtin_amdgcn_mfma_f32_16x16x32_bf16(a0, wf[kc][dt], acc[0][dt], 0, 0, 0);
                acc[1][dt] = __builtin_amdgcn_mfma_f32_16x16x32_bf16(a1, wf[kc][dt], acc[1][dt], 0, 0, 0);
            }
        }
        // VT2: key = r0+mt*16+4*quad+r, col = c0w+dt*16+l15 (d)
#pragma unroll
        for (int mt = 0; mt < 2; ++mt) {
#pragma unroll
            for (int dt = 0; dt < 2; ++dt) {
                const int col = c0w + dt * 16 + l15;
                shortx4 pk;
#pragma unroll
                for (int r = 0; r < 4; ++r) pk[r] = (short)f2bf(acc[mt][dt][r] + bv[dt]);
                unsigned short* dstp = VT2
                    + ((size_t)((b * 4 + (col >> 6)) * 64 + tl)) * 2048
                    + (col & 63) * 32 + mt * 16 + 4 * quad;
                *(shortx4*)dstp = pk;
            }
        }
    }
}

// Fused QKV projections: grid (512, 2); y=0: Q->Qp, y=1: K->{KT,VT2}.
__global__ __launch_bounds__(256, 4) void qkv_mfma(
        const float* __restrict__ Q, const float* __restrict__ K,
        const unsigned short* __restrict__ WT5,
        const float* __restrict__ bq, const float* __restrict__ bk,
        const float* __restrict__ bv,
        unsigned short* __restrict__ Qp, unsigned short* __restrict__ KT,
        unsigned short* __restrict__ VT2) {
    if (blockIdx.y == 0) q_body(Q, WT5, bq, Qp, blockIdx.x);
    else kv_body(K, WT5 + 65536, WT5 + 131072, bk, bv, KT, VT2, blockIdx.x);
}

// ---------------------------------------------------------------------------
// Flash attention, O^T form, no-max softmax. r20 structure (unchanged):
// Block = 128 q-rows x 512 keys (kq quarter), grid 1024 (4 blocks/CU).
// 4 waves x 32 q-rows each; per tile: read ck/cv ONCE, run QK+softmax+PV
// for both q-subtiles. Double-buffered XOR-swizzled LDS.
// Unnormalized partials Od[kq], Lp[kq]; merge in ffn_fused.
// ---------------------------------------------------------------------------
__global__ __launch_bounds__(256, 2) void attn_mfma(
        const unsigned short* __restrict__ Qp, const unsigned short* __restrict__ KT,
        const unsigned short* __restrict__ VT2, float* __restrict__ Od,
        float* __restrict__ Lp) {
    __shared__ unsigned short kbuf[2][2048];  // K tile double buffer (4KB ea)
    __shared__ unsigned short vbuf[2][2048];  // V tile double buffer
    __shared__ unsigned int pbuf[4][256];     // per-wave P exchange, pitch 16 dw
    const int tid = threadIdx.x;
    const int lane = tid & 63, w = tid >> 6;  // w = wave (32 q-rows each)
    const int l15 = lane & 15, quad = lane >> 4;
    const int gb = blockIdx.x;                // 0..1023
    const int bh = ((gb & 7) << 1) | ((gb >> 9) & 1);   // XCD-locality swizzle
    const int qc = (gb >> 3) & 15;
    const int kq = (gb >> 7) & 3;                       // key quarter
    const int h  = bh & 3;
    const int b  = bh >> 2;
    const int qrow = qc * 128 + w * 32;
    const int sw = 4 * ((l15 >> 1) & 3);                // pbuf bank swizzle

    short8 aq0, aq1, aq2, aq3;
    {
        const unsigned short* qptr = Qp + ((size_t)(b * NN + qrow + l15) * DD + h * DHH + 8 * quad);
        aq0 = *(const short8*)qptr;
        aq1 = *(const short8*)(qptr + 32);
        const unsigned short* qptr2 = qptr + (size_t)16 * DD;
        aq2 = *(const short8*)qptr2;
        aq3 = *(const short8*)(qptr2 + 32);
    }
    fx4 od00 = (fx4){0.f, 0.f, 0.f, 0.f};
    fx4 od01 = (fx4){0.f, 0.f, 0.f, 0.f};
    fx4 od02 = (fx4){0.f, 0.f, 0.f, 0.f};
    fx4 od03 = (fx4){0.f, 0.f, 0.f, 0.f};
    fx4 od10 = (fx4){0.f, 0.f, 0.f, 0.f};
    fx4 od11 = (fx4){0.f, 0.f, 0.f, 0.f};
    fx4 od12 = (fx4){0.f, 0.f, 0.f, 0.f};
    fx4 od13 = (fx4){0.f, 0.f, 0.f, 0.f};
    float lsum0 = 0.0f, lsum1 = 0.0f;

    unsigned int* pw = &pbuf[w][0];
    const int wcol = (2 * quad) ^ sw;         // write cols (pairs t=2q,2q+1 / +8)
    const int rcol = (4 * quad) ^ sw;         // read col group (t=4Q..4Q+3)
    const unsigned short* ktb = KT  + (size_t)(bh * 64 + kq * 16) * 2048 + tid * 8;
    const unsigned short* vtb = VT2 + (size_t)(bh * 64 + kq * 16) * 2048 + tid * 8;
    // K/V tile swizzle: element e -> e ^ (((e>>6)&3)<<3)  (byte[5:4]^=byte[8:7])
    const int ew = (tid * 8) ^ (((tid >> 3) & 3) << 3);          // stage-write dst
    const int fo = (l15 * 32 + 8 * quad) ^ (((l15 >> 1) & 3) << 3); // frag-read base

    // prologue: stage tile 0 into buffer 0
    {
        uint4v kr = *(const uint4v*)ktb;
        uint4v vr = *(const uint4v*)vtb;
        *(uint4v*)&kbuf[0][ew] = kr;
        *(uint4v*)&vbuf[0][ew] = vr;
    }
    __syncthreads();

    for (int t = 0; t < 16; ++t) {
        const int cur = t & 1;
        const int tn = (t < 15) ? t + 1 : 15;           // clamp (last redundant)
        // issue next-tile global loads FIRST (T14 async split: write after compute)
        uint4v kr = *(const uint4v*)(ktb + (size_t)tn * 2048);
        uint4v vr = *(const uint4v*)(vtb + (size_t)tn * 2048);

        // ---- compute tile t from LDS (frags read ONCE for 2 q-subtiles) ----
        const unsigned short* kb = &kbuf[cur][fo];
        short8 ck0 = *(const short8*)(kb);          // keys l15,    d 8q..8q+7
        short8 ck1 = *(const short8*)(kb + 1024);   // keys l15,    d 32+8q..
        short8 ck2 = *(const short8*)(kb + 512);    // keys 16+l15, d 8q..
        short8 ck3 = *(const short8*)(kb + 1536);   // keys 16+l15, d 32+8q..
        const unsigned short* vb = &vbuf[cur][fo];
        short8 cv0 = *(const short8*)(vb);          // d l15,    keys 8q..8q+7
        short8 cv1 = *(const short8*)(vb + 512);    // d 16+l15
        short8 cv2 = *(const short8*)(vb + 1024);   // d 32+l15
        short8 cv3 = *(const short8*)(vb + 1536);   // d 48+l15

        const fx4 z_ = (fx4){0.f, 0.f, 0.f, 0.f};
        // QK^T both subtiles
        fx4 s0 = __builtin_amdgcn_mfma_f32_16x16x32_bf16(ck0, aq0, z_, 0, 0, 0);
        s0     = __builtin_amdgcn_mfma_f32_16x16x32_bf16(ck1, aq1, s0, 0, 0, 0);
        fx4 s1 = __builtin_amdgcn_mfma_f32_16x16x32_bf16(ck2, aq0, z_, 0, 0, 0);
        s1     = __builtin_amdgcn_mfma_f32_16x16x32_bf16(ck3, aq1, s1, 0, 0, 0);
        fx4 s2 = __builtin_amdgcn_mfma_f32_16x16x32_bf16(ck0, aq2, z_, 0, 0, 0);
        s2     = __builtin_amdgcn_mfma_f32_16x16x32_bf16(ck1, aq3, s2, 0, 0, 0);
        fx4 s3 = __builtin_amdgcn_mfma_f32_16x16x32_bf16(ck2, aq2, z_, 0, 0, 0);
        s3     = __builtin_amdgcn_mfma_f32_16x16x32_bf16(ck3, aq3, s3, 0, 0, 0);
        s0[0] = __expf(s0[0] * 0.125f); s0[1] = __expf(s0[1] * 0.125f);
        s0[2] = __expf(s0[2] * 0.125f); s0[3] = __expf(s0[3] * 0.125f);
        s1[0] = __expf(s1[0] * 0.125f); s1[1] = __expf(s1[1] * 0.125f);
        s1[2] = __expf(s1[2] * 0.125f); s1[3] = __expf(s1[3] * 0.125f);
        s2[0] = __expf(s2[0] * 0.125f); s2[1] = __expf(s2[1] * 0.125f);
        s2[2] = __expf(s2[2] * 0.125f); s2[3] = __expf(s2[3] * 0.125f);
        s3[0] = __expf(s3[0] * 0.125f); s3[1] = __expf(s3[1] * 0.125f);
        s3[2] = __expf(s3[2] * 0.125f); s3[3] = __expf(s3[3] * 0.125f);
        lsum0 += s0[0] + s0[1] + s0[2] + s0[3] + s1[0] + s1[1] + s1[2] + s1[3];
        lsum1 += s2[0] + s2[1] + s2[2] + s2[3] + s3[0] + s3[1] + s3[2] + s3[3];
        // exchange + PV, subtile 0
        {
            uint2v w1_ = (uint2v){packbf(s0[0], s0[1]), packbf(s0[2], s0[3])};
            uint2v w2_ = (uint2v){packbf(s1[0], s1[1]), packbf(s1[2], s1[3])};
            *(uint2v*)(pw + l15 * 16 + wcol)       = w1_;
            *(uint2v*)(pw + l15 * 16 + (wcol ^ 8)) = w2_;
            short8 bp = *(const short8*)(pw + l15 * 16 + rcol);
            od00 = __builtin_amdgcn_mfma_f32_16x16x32_bf16(cv0, bp, od00, 0, 0, 0);
            od01 = __builtin_amdgcn_mfma_f32_16x16x32_bf16(cv1, bp, od01, 0, 0, 0);
            od02 = __builtin_amdgcn_mfma_f32_16x16x32_bf16(cv2, bp, od02, 0, 0, 0);
            od03 = __builtin_amdgcn_mfma_f32_16x16x32_bf16(cv3, bp, od03, 0, 0, 0);
        }
        // exchange + PV, subtile 1 (same pbuf region, wave-sequential)
        {
            uint2v w1_ = (uint2v){packbf(s2[0], s2[1]), packbf(s2[2], s2[3])};
            uint2v w2_ = (uint2v){packbf(s3[0], s3[1]), packbf(s3[2], s3[3])};
            *(uint2v*)(pw + l15 * 16 + wcol)       = w1_;
            *(uint2v*)(pw + l15 * 16 + (wcol ^ 8)) = w2_;
            short8 bp = *(const short8*)(pw + l15 * 16 + rcol);
            od10 = __builtin_amdgcn_mfma_f32_16x16x32_bf16(cv0, bp, od10, 0, 0, 0);
            od11 = __builtin_amdgcn_mfma_f32_16x16x32_bf16(cv1, bp, od11, 0, 0, 0);
            od12 = __builtin_amdgcn_mfma_f32_16x16x32_bf16(cv2, bp, od12, 0, 0, 0);
            od13 = __builtin_amdgcn_mfma_f32_16x16x32_bf16(cv3, bp, od13, 0, 0, 0);
        }

        // ---- land next tile into the other buffer, then sync ----
        *(uint4v*)&kbuf[cur ^ 1][ew] = kr;
        *(uint4v*)&vbuf[cur ^ 1][ew] = vr;
        __syncthreads();
    }

    // per-q partial l (sum over quads); write UNNORMALIZED partials
    lsum0 += __shfl_xor(lsum0, 16);
    lsum0 += __shfl_xor(lsum0, 32);
    lsum1 += __shfl_xor(lsum1, 16);
    lsum1 += __shfl_xor(lsum1, 32);
    const size_t grow0 = (size_t)(b * NN) + qrow + l15;
    const size_t grow1 = grow0 + 16;
    float* ob0 = Od + (size_t)kq * 2097152 + grow0 * DD + h * DHH;
    *(fx4*)(ob0 + 0 * 16 + 4 * quad) = od00;
    *(fx4*)(ob0 + 1 * 16 + 4 * quad) = od01;
    *(fx4*)(ob0 + 2 * 16 + 4 * quad) = od02;
    *(fx4*)(ob0 + 3 * 16 + 4 * quad) = od03;
    float* ob1 = Od + (size_t)kq * 2097152 + grow1 * DD + h * DHH;
    *(fx4*)(ob1 + 0 * 16 + 4 * quad) = od10;
    *(fx4*)(ob1 + 1 * 16 + 4 * quad) = od11;
    *(fx4*)(ob1 + 2 * 16 + 4 * quad) = od12;
    *(fx4*)(ob1 + 3 * 16 + 4 * quad) = od13;
    if (quad == 0) {
        Lp[(size_t)kq * 32768 + grow0 * 4 + h] = lsum0;
        Lp[(size_t)kq * 32768 + grow1 * 4 + h] = lsum1;
    }
}

// ---------------------------------------------------------------------------
// Fused FFN: merge(Od)/l + Qp residual + LN0 -> Osh (LDS fp32) + As (bf16);
// ffn1 MFMA -> relu -> Hs (LDS); ffn2 MFMA -> +b2 + Osh -> LN1 -> out.
// Block = 32 rows, 512 thr, 8 waves (32 cols each). O never hits global.
// ---------------------------------------------------------------------------
__global__ __launch_bounds__(512) void ffn_fused(
        const float* __restrict__ Od, const float* __restrict__ Lp,
        const unsigned short* __restrict__ Qp,
        const float* __restrict__ g0, const float* __restrict__ be0,
        const unsigned short* __restrict__ WT1, const float* __restrict__ b1,
        const unsigned short* __restrict__ WT2, const float* __restrict__ b2,
        const float* __restrict__ g1, const float* __restrict__ be1,
        float* __restrict__ out) {
    __shared__ unsigned short As[32 * 264];   // LN0(O) bf16 (ffn1 A)
    __shared__ unsigned short Hs[32 * 264];   // H1 bf16 (ffn2 A)
    __shared__ float Osh[32 * 260];           // LN0(O) fp32 (phase-3 residual)
    __shared__ float lnb[2][8][32];
    const int tid = threadIdx.x;
    const int lane = tid & 63, w = tid >> 6;          // w in 0..7
    const int l15 = lane & 15, quad = lane >> 4;
    const int r0 = blockIdx.x * 32;
    const int c0w = w * 32;
    {   // ---- phase 1: merge + residual + LN0; row = tid>>4, 16 elems ----
        const int row = tid >> 4, c0 = (tid & 15) * 16;
        const size_t grow = r0 + row;
        const int hh = c0 >> 6;
        const float inv = 1.0f / (Lp[grow * 4 + hh] + Lp[32768 + grow * 4 + hh]
                                + Lp[65536 + grow * 4 + hh] + Lp[98304 + grow * 4 + hh]);
        float v[16];
        float s1 = 0.f, s2 = 0.f;
        const float* odp = Od + grow * DD + c0;
#pragma unroll
        for (int j = 0; j < 4; ++j) {
            fx4 m0 = *(const fx4*)(odp + j * 4);
            fx4 m1 = *(const fx4*)(odp + 2097152 + j * 4);
            fx4 m2 = *(const fx4*)(odp + 4194304 + j * 4);
            fx4 m3 = *(const fx4*)(odp + 6291456 + j * 4);
            shortx4 qv = *(const shortx4*)(Qp + grow * DD + c0 + j * 4);
#pragma unroll
            for (int i = 0; i < 4; ++i) {
                float x = (m0[i] + m1[i] + m2[i] + m3[i]) * inv
                        + bf2f((unsigned short)qv[i]);
                v[j * 4 + i] = x; s1 += x; s2 += x * x;
            }
        }
        s1 += __shfl_xor(s1, 1); s2 += __shfl_xor(s2, 1);
        s1 += __shfl_xor(s1, 2); s2 += __shfl_xor(s2, 2);
        s1 += __shfl_xor(s1, 4); s2 += __shfl_xor(s2, 4);
        s1 += __shfl_xor(s1, 8); s2 += __shfl_xor(s2, 8);
        const float mean = s1 * (1.0f / 256.0f);
        const float var  = s2 * (1.0f / 256.0f) - mean * mean;
        const float rstd = rsqrtf(var + 1e-5f);
#pragma unroll
        for (int j = 0; j < 4; ++j) {
            fx4 gg = *(const fx4*)(g0 + c0 + j * 4);
            fx4 ee = *(const fx4*)(be0 + c0 + j * 4);
            fx4 o; shortx4 ob;
#pragma unroll
            for (int i = 0; i < 4; ++i) {
                o[i] = (v[j * 4 + i] - mean) * rstd * gg[i] + ee[i];
                ob[i] = (short)f2bf(o[i]);
            }
            *(fx4*)(&Osh[row * 260 + c0 + j * 4]) = o;
            *(shortx4*)(As + row * 264 + c0 + j * 4) = ob;
        }
    }
    // W1 frags + b1
    short8 wf[8][2];
#pragma unroll
    for (int kc = 0; kc < 8; ++kc)
#pragma unroll
        for (int dt = 0; dt < 2; ++dt)
            wf[kc][dt] = *(const short8*)(WT1 + (size_t)(c0w + dt * 16 + l15) * DD + kc * 32 + 8 * quad);
    fx4 bb1[2];
#pragma unroll
    for (int dt = 0; dt < 2; ++dt)
        bb1[dt] = *(const fx4*)(b1 + c0w + dt * 16 + 4 * quad);
    __syncthreads();
    // ---- phase 2: ffn1 MFMA -> relu -> Hs ----
    fx4 acc[2][2];
#pragma unroll
    for (int mt = 0; mt < 2; ++mt)
#pragma unroll
        for (int dt = 0; dt < 2; ++dt) acc[mt][dt] = (fx4){0.f, 0.f, 0.f, 0.f};
#pragma unroll
    for (int kc = 0; kc < 8; ++kc) {
        short8 a0 = *(const short8*)(As + l15 * 264 + kc * 32 + 8 * quad);
        short8 a1 = *(const short8*)(As + (16 + l15) * 264 + kc * 32 + 8 * quad);
#pragma unroll
        for (int dt = 0; dt < 2; ++dt) {
            acc[0][dt] = __builtin_amdgcn_mfma_f32_16x16x32_bf16(wf[kc][dt], a0, acc[0][dt], 0, 0, 0);
            acc[1][dt] = __builtin_amdgcn_mfma_f32_16x16x32_bf16(wf[kc][dt], a1, acc[1][dt], 0, 0, 0);
        }
    }
#pragma unroll
    for (int mt = 0; mt < 2; ++mt) {
#pragma unroll
        for (int dt = 0; dt < 2; ++dt) {
            shortx4 pk;
#pragma unroll
            for (int r = 0; r < 4; ++r)
                pk[r] = (short)f2bf(fmaxf(acc[mt][dt][r] + bb1[dt][r], 0.0f));
            *(shortx4*)(Hs + (mt * 16 + l15) * 264 + c0w + dt * 16 + 4 * quad) = pk;
        }
    }
    // W2 frags + b2 + g1/be1
    short8 wf2[8][2];
#pragma unroll
    for (int kc = 0; kc < 8; ++kc)
#pragma unroll
        for (int dt = 0; dt < 2; ++dt)
            wf2[kc][dt] = *(const short8*)(WT2 + (size_t)(c0w + dt * 16 + l15) * DD + kc * 32 + 8 * quad);
    fx4 bb2[2], gg1[2], ee1[2];
#pragma unroll
    for (int dt = 0; dt < 2; ++dt) {
        int col = c0w + dt * 16 + 4 * quad;
        bb2[dt] = *(const fx4*)(b2 + col);
        gg1[dt] = *(const fx4*)(g1 + col);
        ee1[dt] = *(const fx4*)(be1 + col);
    }
    __syncthreads();
    // ---- phase 3: ffn2 MFMA -> +b2 + Osh residual -> LN1 -> out ----
    fx4 acc2[2][2];
#pragma unroll
    for (int mt = 0; mt < 2; ++mt)
#pragma unroll
        for (int dt = 0; dt < 2; ++dt) acc2[mt][dt] = (fx4){0.f, 0.f, 0.f, 0.f};
#pragma unroll
    for (int kc = 0; kc < 8; ++kc) {
        short8 a0 = *(const short8*)(Hs + l15 * 264 + kc * 32 + 8 * quad);
        short8 a1 = *(const short8*)(Hs + (16 + l15) * 264 + kc * 32 + 8 * quad);
#pragma unroll
        for (int dt = 0; dt < 2; ++dt) {
            acc2[0][dt] = __builtin_amdgcn_mfma_f32_16x16x32_bf16(wf2[kc][dt], a0, acc2[0][dt], 0, 0, 0);
            acc2[1][dt] = __builtin_amdgcn_mfma_f32_16x16x32_bf16(wf2[kc][dt], a1, acc2[1][dt], 0, 0, 0);
        }
    }
    fx4 v4[2][2];
#pragma unroll
    for (int mt = 0; mt < 2; ++mt) {
        const int lrow = mt * 16 + l15;
        float p1 = 0.f, p2 = 0.f;
#pragma unroll
        for (int dt = 0; dt < 2; ++dt) {
            fx4 rv = *(const fx4*)(&Osh[lrow * 260 + c0w + dt * 16 + 4 * quad]);
#pragma unroll
            for (int r = 0; r < 4; ++r) {
                float x = acc2[mt][dt][r] + bb2[dt][r] + rv[r];
                v4[mt][dt][r] = x; p1 += x; p2 += x * x;
            }
        }
        p1 += __shfl_xor(p1, 16); p2 += __shfl_xor(p2, 16);
        p1 += __shfl_xor(p1, 32); p2 += __shfl_xor(p2, 32);
        if (quad == 0) { lnb[0][w][lrow] = p1; lnb[1][w][lrow] = p2; }
    }
    __syncthreads();
#pragma unroll
    for (int mt = 0; mt < 2; ++mt) {
        const int row = mt * 16 + l15;
        float s1 = 0.f, s2 = 0.f;
#pragma unroll
        for (int ww = 0; ww < 8; ++ww) { s1 += lnb[0][ww][row]; s2 += lnb[1][ww][row]; }
        const float mean = s1 * (1.0f / 256.0f);
        const float var  = s2 * (1.0f / 256.0f) - mean * mean;
        const float rstd = rsqrtf(var + 1e-5f);
        const size_t grow = r0 + row;
#pragma unroll
        for (int dt = 0; dt < 2; ++dt) {
            fx4 o;
#pragma unroll
            for (int r = 0; r < 4; ++r)
                o[r] = (v4[mt][dt][r] - mean) * rstd * gg1[dt][r] + ee1[dt][r];
            *(fx4*)(out + grow * DD + c0w + dt * 16 + 4 * quad) = o;
        }
    }
}

extern "C" void kernel_launch(void* const* d_in, const int* in_sizes, int n_in,
                              void* d_out, int out_size, void* d_ws, size_t ws_size,
                              hipStream_t stream) {
    (void)in_sizes; (void)n_in; (void)out_size; (void)ws_size;
    const float* Q     = (const float*)d_in[0];
    const float* K     = (const float*)d_in[1];
    const float* Wq    = (const float*)d_in[2];
    const float* bq    = (const float*)d_in[3];
    const float* Wk    = (const float*)d_in[4];
    const float* bk    = (const float*)d_in[5];
    const float* Wv    = (const float*)d_in[6];
    const float* bv    = (const float*)d_in[7];
    const float* W1    = (const float*)d_in[8];
    const float* b1    = (const float*)d_in[9];
    const float* W2    = (const float*)d_in[10];
    const float* b2    = (const float*)d_in[11];
    const float* g0    = (const float*)d_in[12];
    const float* beta0 = (const float*)d_in[13];
    const float* g1    = (const float*)d_in[14];
    const float* beta1 = (const float*)d_in[15];

    // Workspace: [0,4)Mi Qp bf16; [4,8)Mi KT; [8,12)Mi VT2; [12,44)Mi Od[4];
    // [44,+512K) Lp; [45Mi,+640K) WT x5
    char* ws = (char*)d_ws;
    unsigned short* Qp  = (unsigned short*)(ws);
    unsigned short* KT  = (unsigned short*)(ws + (4u  << 20));
    unsigned short* VT2 = (unsigned short*)(ws + (8u  << 20));
    float*          Od  = (float*)(ws + (12u << 20));   // 4 x 8MB partials
    float*          Lp  = (float*)(ws + (44u << 20));
    unsigned short* WT5 = (unsigned short*)(ws + (45u << 20));
    float*          out = (float*)d_out;

    const unsigned short* WT1 = WT5 + 3 * 65536;
    const unsigned short* WT2 = WT5 + 4 * 65536;

    const int M = BB * NN;                        // 8192 rows

    wt_prep<<<dim3(4, 4, 5), 256, 0, stream>>>(Wq, Wk, Wv, W1, W2, WT5);
    qkv_mfma<<<dim3(M / 16, 2), 256, 0, stream>>>(Q, K, WT5, bq, bk, bv, Qp, KT, VT2);
    attn_mfma<<<1024, 256, 0, stream>>>(Qp, KT, VT2, Od, Lp);
    ffn_fused<<<M / 32, 512, 0, stream>>>(Od, Lp, Qp, g0, beta0, WT1, b1,
                                          WT2, b2, g1, beta1, out);
}